// Round 2
// baseline (5556.239 us; speedup 1.0000x reference)
//
#include <hip/hip_runtime.h>
#include <math.h>

#define NN 30000
#define NE 480000
#define DF 256
#define DH 256
#define NH (NN * DH)   // 7,680,000 elements per output tensor

static __device__ __forceinline__ float sigmoidf_(float x) {
    return 1.0f / (1.0f + __expf(-x));
}

// deg[src[e]] += w[e]
__global__ void deg_kernel(const int* __restrict__ src, const float* __restrict__ w,
                           float* __restrict__ deg) {
    int e = blockIdx.x * blockDim.x + threadIdx.x;
    if (e < NE) atomicAdd(&deg[src[e]], w[e]);
}

// deg -> dinv in place
__global__ void dinv_kernel(float* __restrict__ deg) {
    int v = blockIdx.x * blockDim.x + threadIdx.x;
    if (v < NN) {
        float d = deg[v];
        deg[v] = (d > 0.0f) ? rsqrtf(fmaxf(d, 1e-12f)) : 0.0f;
    }
}

// x_new[src[e]] += x[snf[e]] ; x_new[dst[e]] += x[dnf[e]]   (one wave per scatter-op)
__global__ void augment_kernel(const float* __restrict__ x, float* __restrict__ x_new,
                               const int* __restrict__ src, const int* __restrict__ dst,
                               const int* __restrict__ snf, const int* __restrict__ dnf) {
    int wave = (blockIdx.x * blockDim.x + threadIdx.x) >> 6;
    int lane = threadIdx.x & 63;
    if (wave >= 2 * NE) return;
    int tgt, nbr;
    if (wave < NE) { tgt = src[wave];      nbr = snf[wave]; }
    else           { int e = wave - NE; tgt = dst[e]; nbr = dnf[e]; }
    const float4 v = *reinterpret_cast<const float4*>(&x[(size_t)nbr * DF + lane * 4]);
    float* p = &x_new[(size_t)tgt * DF + lane * 4];
    atomicAdd(p + 0, v.x); atomicAdd(p + 1, v.y);
    atomicAdd(p + 2, v.z); atomicAdd(p + 3, v.w);
}

// t1[dst[e]] += norm_e * h[src[e]]   (one wave per edge)
__global__ void t1_kernel(const float* __restrict__ h, float* __restrict__ t1,
                          const int* __restrict__ src, const int* __restrict__ dst,
                          const float* __restrict__ w, const float* __restrict__ dinv) {
    int wave = (blockIdx.x * blockDim.x + threadIdx.x) >> 6;
    int lane = threadIdx.x & 63;
    if (wave >= NE) return;
    int s = src[wave], d = dst[wave];
    float nrm = -dinv[s] * w[wave] * dinv[d];
    const float4 v = *reinterpret_cast<const float4*>(&h[(size_t)s * DH + lane * 4]);
    float* p = &t1[(size_t)d * DH + lane * 4];
    atomicAdd(p + 0, nrm * v.x); atomicAdd(p + 1, nrm * v.y);
    atomicAdd(p + 2, nrm * v.z); atomicAdd(p + 3, nrm * v.w);
}

// Pack B into Wcat[768][1024]: rows 0-255 = W_*, 256-511 = Wc_*[0], 512-767 = Wc_*[1];
// cols [0:256)=i, [256:512)=f, [512:768)=g, [768:1024)=o
__global__ void wcat_kernel(const float* __restrict__ W_i, const float* __restrict__ W_f,
                            const float* __restrict__ W_g, const float* __restrict__ W_o,
                            const float* __restrict__ Wc_i, const float* __restrict__ Wc_f,
                            const float* __restrict__ Wc_g, const float* __restrict__ Wc_o,
                            float* __restrict__ Wcat) {
    int idx = blockIdx.x * blockDim.x + threadIdx.x;
    if (idx >= 768 * 1024) return;
    int k = idx >> 10, n = idx & 1023;
    int seg = k >> 8, kk = k & 255, gate = n >> 8, nn = n & 255;
    const float* p;
    if (seg == 0) {
        p = (gate == 0) ? W_i : (gate == 1) ? W_f : (gate == 2) ? W_g : W_o;
    } else {
        const float* base = (gate == 0) ? Wc_i : (gate == 1) ? Wc_f : (gate == 2) ? Wc_g : Wc_o;
        p = base + (seg - 1) * 256 * 256;
    }
    Wcat[idx] = p[kk * 256 + nn];
}

// pre[M x 1024] = [A0|A1|A2] (M x 768) @ Wcat (768 x 1024)
__global__ __launch_bounds__(256) void gemm_pre(const float* __restrict__ A0,
                                                const float* __restrict__ A1,
                                                const float* __restrict__ A2,
                                                const float* __restrict__ Wcat,
                                                float* __restrict__ pre) {
    __shared__ float As[16][68];  // [k][m], transposed store
    __shared__ float Bs[16][68];  // [k][n]
    int bm = blockIdx.x * 64;
    int bn = blockIdx.y * 64;
    int tid = threadIdx.x;
    int tx = tid & 15, ty = tid >> 4;
    float acc[4][4] = {};
    const float* Aseg[3] = {A0, A1, A2};
    for (int seg = 0; seg < 3; ++seg) {
        const float* __restrict__ A = Aseg[seg];
        for (int kt = 0; kt < 256; kt += 16) {
            {   // A tile 64x16
                int r = tid >> 2, c0 = (tid & 3) * 4, row = bm + r;
                float4 a = (row < NN) ? *reinterpret_cast<const float4*>(&A[(size_t)row * 256 + kt + c0])
                                      : make_float4(0.f, 0.f, 0.f, 0.f);
                As[c0 + 0][r] = a.x; As[c0 + 1][r] = a.y;
                As[c0 + 2][r] = a.z; As[c0 + 3][r] = a.w;
            }
            {   // B tile 16x64
                int rb = tid >> 4, cb = (tid & 15) * 4;
                float4 b = *reinterpret_cast<const float4*>(
                    &Wcat[(size_t)(seg * 256 + kt + rb) * 1024 + bn + cb]);
                *reinterpret_cast<float4*>(&Bs[rb][cb]) = b;
            }
            __syncthreads();
            #pragma unroll
            for (int k = 0; k < 16; ++k) {
                float4 av = *reinterpret_cast<const float4*>(&As[k][ty * 4]);
                float4 bv = *reinterpret_cast<const float4*>(&Bs[k][tx * 4]);
                const float a4[4] = {av.x, av.y, av.z, av.w};
                const float b4[4] = {bv.x, bv.y, bv.z, bv.w};
                #pragma unroll
                for (int i = 0; i < 4; ++i)
                    #pragma unroll
                    for (int j = 0; j < 4; ++j)
                        acc[i][j] += a4[i] * b4[j];
            }
            __syncthreads();
        }
    }
    #pragma unroll
    for (int i = 0; i < 4; ++i) {
        int row = bm + ty * 4 + i;
        if (row < NN) {
            float4 o = make_float4(acc[i][0], acc[i][1], acc[i][2], acc[i][3]);
            *reinterpret_cast<float4*>(&pre[(size_t)row * 1024 + bn + tx * 4]) = o;
        }
    }
}

// gates + state update
__global__ void gate_kernel(const float* __restrict__ pre, const float* __restrict__ c,
                            const float* __restrict__ bc_i, const float* __restrict__ bc_f,
                            const float* __restrict__ bc_g, const float* __restrict__ bc_o,
                            const float* __restrict__ b_i, const float* __restrict__ b_f,
                            const float* __restrict__ b_g, const float* __restrict__ b_o,
                            const float* __restrict__ w_ci, const float* __restrict__ w_cf,
                            const float* __restrict__ w_co,
                            float* __restrict__ h0p, float* __restrict__ cnp) {
    int idx = blockIdx.x * blockDim.x + threadIdx.x;
    if (idx >= NN * (DH / 4)) return;
    int row = idx >> 6;
    int n4 = (idx & 63) << 2;
    size_t pb = (size_t)row * 1024;
    float4 pi = *reinterpret_cast<const float4*>(&pre[pb + n4]);
    float4 pf = *reinterpret_cast<const float4*>(&pre[pb + 256 + n4]);
    float4 pg = *reinterpret_cast<const float4*>(&pre[pb + 512 + n4]);
    float4 po = *reinterpret_cast<const float4*>(&pre[pb + 768 + n4]);
    float4 cv = *reinterpret_cast<const float4*>(&c[(size_t)row * 256 + n4]);
    float4 vbci = *reinterpret_cast<const float4*>(&bc_i[n4]);
    float4 vbcf = *reinterpret_cast<const float4*>(&bc_f[n4]);
    float4 vbcg = *reinterpret_cast<const float4*>(&bc_g[n4]);
    float4 vbco = *reinterpret_cast<const float4*>(&bc_o[n4]);
    float4 vbi  = *reinterpret_cast<const float4*>(&b_i[n4]);
    float4 vbf  = *reinterpret_cast<const float4*>(&b_f[n4]);
    float4 vbg  = *reinterpret_cast<const float4*>(&b_g[n4]);
    float4 vbo  = *reinterpret_cast<const float4*>(&b_o[n4]);
    float4 vwci = *reinterpret_cast<const float4*>(&w_ci[n4]);
    float4 vwcf = *reinterpret_cast<const float4*>(&w_cf[n4]);
    float4 vwco = *reinterpret_cast<const float4*>(&w_co[n4]);
    float4 cn4, h04;
    const float* PI = (const float*)&pi;  const float* PF = (const float*)&pf;
    const float* PG = (const float*)&pg;  const float* PO = (const float*)&po;
    const float* CV = (const float*)&cv;
    const float* BCI = (const float*)&vbci; const float* BCF = (const float*)&vbcf;
    const float* BCG = (const float*)&vbcg; const float* BCO = (const float*)&vbco;
    const float* BI = (const float*)&vbi;   const float* BF = (const float*)&vbf;
    const float* BG = (const float*)&vbg;   const float* BO = (const float*)&vbo;
    const float* WCI = (const float*)&vwci; const float* WCF = (const float*)&vwcf;
    const float* WCO = (const float*)&vwco;
    float* CN = (float*)&cn4; float* H0 = (float*)&h04;
    #pragma unroll
    for (int j = 0; j < 4; ++j) {
        float iv = sigmoidf_(PI[j] + BCI[j] + BI[j] + WCI[j] * CV[j]);
        float fv = sigmoidf_(PF[j] + BCF[j] + BF[j] + WCF[j] * CV[j]);
        float gv = tanhf(PG[j] + BCG[j] + BG[j]);
        float cn = fv * CV[j] + iv * gv;
        float ov = sigmoidf_(PO[j] + BCO[j] + BO[j] + WCO[j] * cn);
        CN[j] = cn;
        H0[j] = ov * tanhf(cn);
    }
    *reinterpret_cast<float4*>(&cnp[(size_t)row * 256 + n4]) = cn4;
    *reinterpret_cast<float4*>(&h0p[(size_t)row * 256 + n4]) = h04;
}

// out[M x 256] = relu(A) (M x 256) @ B (256 x 256) + bias
__global__ __launch_bounds__(256) void gemm_lin(const float* __restrict__ A,
                                                const float* __restrict__ B,
                                                const float* __restrict__ bias,
                                                float* __restrict__ out) {
    __shared__ float As[16][68];
    __shared__ float Bs[16][68];
    int bm = blockIdx.x * 64;
    int bn = blockIdx.y * 64;
    int tid = threadIdx.x;
    int tx = tid & 15, ty = tid >> 4;
    float acc[4][4] = {};
    for (int kt = 0; kt < 256; kt += 16) {
        {
            int r = tid >> 2, c0 = (tid & 3) * 4, row = bm + r;
            float4 a = (row < NN) ? *reinterpret_cast<const float4*>(&A[(size_t)row * 256 + kt + c0])
                                  : make_float4(0.f, 0.f, 0.f, 0.f);
            As[c0 + 0][r] = fmaxf(a.x, 0.f); As[c0 + 1][r] = fmaxf(a.y, 0.f);
            As[c0 + 2][r] = fmaxf(a.z, 0.f); As[c0 + 3][r] = fmaxf(a.w, 0.f);
        }
        {
            int rb = tid >> 4, cb = (tid & 15) * 4;
            float4 b = *reinterpret_cast<const float4*>(&B[(size_t)(kt + rb) * 256 + bn + cb]);
            *reinterpret_cast<float4*>(&Bs[rb][cb]) = b;
        }
        __syncthreads();
        #pragma unroll
        for (int k = 0; k < 16; ++k) {
            float4 av = *reinterpret_cast<const float4*>(&As[k][ty * 4]);
            float4 bv = *reinterpret_cast<const float4*>(&Bs[k][tx * 4]);
            const float a4[4] = {av.x, av.y, av.z, av.w};
            const float b4[4] = {bv.x, bv.y, bv.z, bv.w};
            #pragma unroll
            for (int i = 0; i < 4; ++i)
                #pragma unroll
                for (int j = 0; j < 4; ++j)
                    acc[i][j] += a4[i] * b4[j];
        }
        __syncthreads();
    }
    float4 bb = *reinterpret_cast<const float4*>(&bias[bn + tx * 4]);
    const float* BB = (const float*)&bb;
    #pragma unroll
    for (int i = 0; i < 4; ++i) {
        int row = bm + ty * 4 + i;
        if (row < NN) {
            float4 o = make_float4(acc[i][0] + BB[0], acc[i][1] + BB[1],
                                   acc[i][2] + BB[2], acc[i][3] + BB[3]);
            *reinterpret_cast<float4*>(&out[(size_t)row * 256 + bn + tx * 4]) = o;
        }
    }
}

extern "C" void kernel_launch(void* const* d_in, const int* in_sizes, int n_in,
                              void* d_out, int out_size, void* d_ws, size_t ws_size,
                              hipStream_t stream) {
    const float* x   = (const float*)d_in[0];
    const int*   ei  = (const int*)d_in[1];
    const float* ew  = (const float*)d_in[2];
    const float* h   = (const float*)d_in[3];
    const float* c   = (const float*)d_in[4];
    const int*   snf = (const int*)d_in[5];
    const int*   dnf = (const int*)d_in[6];
    const float* W_i = (const float*)d_in[7];
    const float* W_f = (const float*)d_in[8];
    const float* W_g = (const float*)d_in[9];
    const float* W_o = (const float*)d_in[10];
    const float* Wc_i = (const float*)d_in[11];
    const float* Wc_f = (const float*)d_in[12];
    const float* Wc_g = (const float*)d_in[13];
    const float* Wc_o = (const float*)d_in[14];
    const float* bc_i = (const float*)d_in[15];
    const float* bc_f = (const float*)d_in[16];
    const float* bc_g = (const float*)d_in[17];
    const float* bc_o = (const float*)d_in[18];
    const float* b_i  = (const float*)d_in[19];
    const float* b_f  = (const float*)d_in[20];
    const float* b_g  = (const float*)d_in[21];
    const float* b_o  = (const float*)d_in[22];
    const float* b_lin = (const float*)d_in[23];
    const float* w_ci = (const float*)d_in[24];
    const float* w_cf = (const float*)d_in[25];
    const float* w_co = (const float*)d_in[26];
    const float* W_lin = (const float*)d_in[27];

    const int* src = ei;        // edge_index[0]
    const int* dst = ei + NE;   // edge_index[1]

    float* out = (float*)d_out;
    float* houtp = out;           // final h_out; temporarily x_new
    float* h0p   = out + NH;      // h0
    float* cnp   = out + 2 * NH;  // final c_new; temporarily t1

    // workspace layout
    char* ws = (char*)d_ws;
    float* deg  = (float*)ws;                    // 131072 B (padded)
    float* Wcat = (float*)(ws + 131072);         // 768*1024*4 = 3,145,728 B
    float* pre  = (float*)(ws + 131072 + 3145728); // 30000*1024*4 B

    float* x_new = houtp;  // alias: dead before gemm_lin writes h_out
    float* t1    = cnp;    // alias: dead before gate_kernel writes c_new

    // 1. init
    hipMemsetAsync(deg, 0, 131072, stream);
    hipMemsetAsync(t1, 0, (size_t)NH * 4, stream);
    hipMemcpyAsync(x_new, x, (size_t)NH * 4, hipMemcpyDeviceToDevice, stream);

    // 2. degree + dinv
    deg_kernel<<<(NE + 255) / 256, 256, 0, stream>>>(src, ew, deg);
    dinv_kernel<<<(NN + 255) / 256, 256, 0, stream>>>(deg);

    // 3. neighbor-feature augmentation (atomics)
    augment_kernel<<<(2 * NE) / 4, 256, 0, stream>>>(x, x_new, src, dst, snf, dnf);

    // 4. t1 = segment_sum(norm * h[src], dst)
    t1_kernel<<<NE / 4, 256, 0, stream>>>(h, t1, src, dst, ew, deg);

    // 5. pack weights, big GEMM
    wcat_kernel<<<(768 * 1024) / 256, 256, 0, stream>>>(W_i, W_f, W_g, W_o,
                                                        Wc_i, Wc_f, Wc_g, Wc_o, Wcat);
    dim3 g1((NN + 63) / 64, 1024 / 64);
    gemm_pre<<<g1, 256, 0, stream>>>(x_new, h, t1, Wcat, pre);

    // 6. gates -> h0, c_new (overwrites t1 region)
    gate_kernel<<<(NN * 64 + 255) / 256, 256, 0, stream>>>(
        pre, c, bc_i, bc_f, bc_g, bc_o, b_i, b_f, b_g, b_o, w_ci, w_cf, w_co, h0p, cnp);

    // 7. h_out = relu(h0) @ W_lin + b_lin (overwrites x_new region)
    dim3 g2((NN + 63) / 64, 256 / 64);
    gemm_lin<<<g2, 256, 0, stream>>>(h0p, W_lin, b_lin, houtp);
}

// Round 3
// 1236.869 us; speedup vs baseline: 4.4922x; 4.4922x over previous
//
#include <hip/hip_runtime.h>
#include <math.h>

#define NN 30000
#define NE 480000
#define DF 256
#define DH 256
#define NH (NN * DH)   // 7,680,000 elements per output tensor

static __device__ __forceinline__ float sigmoidf_(float x) {
    return 1.0f / (1.0f + __expf(-x));
}

// deg[src[e]] += w[e]  (480K scalar atomics — cheap)
__global__ void deg_kernel(const int* __restrict__ src, const float* __restrict__ w,
                           float* __restrict__ deg) {
    int e = blockIdx.x * blockDim.x + threadIdx.x;
    if (e < NE) atomicAdd(&deg[src[e]], w[e]);
}

// deg -> dinv in place
__global__ void dinv_kernel(float* __restrict__ deg) {
    int v = blockIdx.x * blockDim.x + threadIdx.x;
    if (v < NN) {
        float d = deg[v];
        deg[v] = (d > 0.0f) ? rsqrtf(fmaxf(d, 1e-12f)) : 0.0f;
    }
}

// count incidence entries per target node
// cnt1[v] = #{e: src[e]==v} + #{e: dst[e]==v}   (augment CSR, 2*NE entries)
// cnt2[v] = #{e: dst[e]==v}                     (t1 CSR, NE entries)
__global__ void count_kernel(const int* __restrict__ src, const int* __restrict__ dst,
                             int* __restrict__ cnt1, int* __restrict__ cnt2) {
    int e = blockIdx.x * blockDim.x + threadIdx.x;
    if (e >= NE) return;
    atomicAdd(&cnt1[src[e]], 1);
    atomicAdd(&cnt1[dst[e]], 1);
    atomicAdd(&cnt2[dst[e]], 1);
}

// single-block exclusive scan over NN elements, twice (cnt1->row1/cur1, cnt2->row2/cur2)
#define SCAN_T 1024
#define SCAN_CH 30   // ceil(30000/1024) = 30
__global__ __launch_bounds__(SCAN_T) void scan_kernel(const int* __restrict__ cnt1,
                                                      const int* __restrict__ cnt2,
                                                      int* __restrict__ row1, int* __restrict__ cur1,
                                                      int* __restrict__ row2, int* __restrict__ cur2) {
    __shared__ int part[SCAN_T];
    int t = threadIdx.x;
    // ---- pass A: cnt1 ----
    {
        int base = t * SCAN_CH;
        int vals[SCAN_CH];
        int local = 0;
        #pragma unroll
        for (int i = 0; i < SCAN_CH; ++i) {
            int idx = base + i;
            int v = (idx < NN) ? cnt1[idx] : 0;
            vals[i] = v; local += v;
        }
        part[t] = local;
        __syncthreads();
        for (int off = 1; off < SCAN_T; off <<= 1) {
            int v = part[t];
            int add = (t >= off) ? part[t - off] : 0;
            __syncthreads();
            part[t] = v + add;
            __syncthreads();
        }
        int run = (t == 0) ? 0 : part[t - 1];
        #pragma unroll
        for (int i = 0; i < SCAN_CH; ++i) {
            int idx = base + i;
            if (idx < NN) { row1[idx] = run; cur1[idx] = run; }
            run += vals[i];
        }
        if (t == SCAN_T - 1) row1[NN] = run;  // == 2*NE
    }
    __syncthreads();
    // ---- pass B: cnt2 ----
    {
        int base = t * SCAN_CH;
        int vals[SCAN_CH];
        int local = 0;
        #pragma unroll
        for (int i = 0; i < SCAN_CH; ++i) {
            int idx = base + i;
            int v = (idx < NN) ? cnt2[idx] : 0;
            vals[i] = v; local += v;
        }
        part[t] = local;
        __syncthreads();
        for (int off = 1; off < SCAN_T; off <<= 1) {
            int v = part[t];
            int add = (t >= off) ? part[t - off] : 0;
            __syncthreads();
            part[t] = v + add;
            __syncthreads();
        }
        int run = (t == 0) ? 0 : part[t - 1];
        #pragma unroll
        for (int i = 0; i < SCAN_CH; ++i) {
            int idx = base + i;
            if (idx < NN) { row2[idx] = run; cur2[idx] = run; }
            run += vals[i];
        }
        if (t == SCAN_T - 1) row2[NN] = run;  // == NE
    }
}

// fill adjacency: adj1[target-sorted] = neighbor-feature node id; adj2[dst-sorted] = edge id
__global__ void scatter_kernel(const int* __restrict__ src, const int* __restrict__ dst,
                               const int* __restrict__ snf, const int* __restrict__ dnf,
                               int* __restrict__ cur1, int* __restrict__ cur2,
                               int* __restrict__ adj1, int* __restrict__ adj2) {
    int e = blockIdx.x * blockDim.x + threadIdx.x;
    if (e >= NE) return;
    int s = src[e], d = dst[e];
    int p1 = atomicAdd(&cur1[s], 1); adj1[p1] = snf[e];
    int p2 = atomicAdd(&cur1[d], 1); adj1[p2] = dnf[e];
    int p3 = atomicAdd(&cur2[d], 1); adj2[p3] = e;
}

// x_new[v] = x[v] + sum_{j in row1[v]..row1[v+1]} x[adj1[j]]   (one wave per node)
__global__ __launch_bounds__(256) void augment_gather(const float* __restrict__ x,
                                                      const int* __restrict__ row1,
                                                      const int* __restrict__ adj1,
                                                      float* __restrict__ x_new) {
    int wid = (blockIdx.x * blockDim.x + threadIdx.x) >> 6;
    int lane = threadIdx.x & 63;
    if (wid >= NN) return;
    int beg = row1[wid], end = row1[wid + 1];
    float4 acc = *reinterpret_cast<const float4*>(&x[(size_t)wid * DF + lane * 4]);
    for (int j = beg; j < end; ++j) {
        int nbr = adj1[j];
        const float4 v = *reinterpret_cast<const float4*>(&x[(size_t)nbr * DF + lane * 4]);
        acc.x += v.x; acc.y += v.y; acc.z += v.z; acc.w += v.w;
    }
    *reinterpret_cast<float4*>(&x_new[(size_t)wid * DF + lane * 4]) = acc;
}

// t1[v] = sum_{e: dst[e]==v} (-dinv[src[e]]*w[e]*dinv[v]) * h[src[e]]   (one wave per node)
__global__ __launch_bounds__(256) void t1_gather(const float* __restrict__ h,
                                                 const int* __restrict__ row2,
                                                 const int* __restrict__ adj2,
                                                 const int* __restrict__ src,
                                                 const float* __restrict__ w,
                                                 const float* __restrict__ dinv,
                                                 float* __restrict__ t1) {
    int wid = (blockIdx.x * blockDim.x + threadIdx.x) >> 6;
    int lane = threadIdx.x & 63;
    if (wid >= NN) return;
    int beg = row2[wid], end = row2[wid + 1];
    float dv = dinv[wid];
    float4 acc = make_float4(0.f, 0.f, 0.f, 0.f);
    for (int j = beg; j < end; ++j) {
        int e = adj2[j];
        int s = src[e];
        float nrm = -dinv[s] * w[e] * dv;
        const float4 v = *reinterpret_cast<const float4*>(&h[(size_t)s * DH + lane * 4]);
        acc.x += nrm * v.x; acc.y += nrm * v.y;
        acc.z += nrm * v.z; acc.w += nrm * v.w;
    }
    *reinterpret_cast<float4*>(&t1[(size_t)wid * DH + lane * 4]) = acc;
}

// Pack B into Wcat[768][1024]: rows 0-255 = W_*, 256-511 = Wc_*[0], 512-767 = Wc_*[1];
// cols [0:256)=i, [256:512)=f, [512:768)=g, [768:1024)=o
__global__ void wcat_kernel(const float* __restrict__ W_i, const float* __restrict__ W_f,
                            const float* __restrict__ W_g, const float* __restrict__ W_o,
                            const float* __restrict__ Wc_i, const float* __restrict__ Wc_f,
                            const float* __restrict__ Wc_g, const float* __restrict__ Wc_o,
                            float* __restrict__ Wcat) {
    int idx = blockIdx.x * blockDim.x + threadIdx.x;
    if (idx >= 768 * 1024) return;
    int k = idx >> 10, n = idx & 1023;
    int seg = k >> 8, kk = k & 255, gate = n >> 8, nn = n & 255;
    const float* p;
    if (seg == 0) {
        p = (gate == 0) ? W_i : (gate == 1) ? W_f : (gate == 2) ? W_g : W_o;
    } else {
        const float* base = (gate == 0) ? Wc_i : (gate == 1) ? Wc_f : (gate == 2) ? Wc_g : Wc_o;
        p = base + (seg - 1) * 256 * 256;
    }
    Wcat[idx] = p[kk * 256 + nn];
}

// pre[M x 1024] = [A0|A1|A2] (M x 768) @ Wcat (768 x 1024)
__global__ __launch_bounds__(256) void gemm_pre(const float* __restrict__ A0,
                                                const float* __restrict__ A1,
                                                const float* __restrict__ A2,
                                                const float* __restrict__ Wcat,
                                                float* __restrict__ pre) {
    __shared__ float As[16][68];  // [k][m], transposed store
    __shared__ float Bs[16][68];  // [k][n]
    int bm = blockIdx.x * 64;
    int bn = blockIdx.y * 64;
    int tid = threadIdx.x;
    int tx = tid & 15, ty = tid >> 4;
    float acc[4][4] = {};
    const float* Aseg[3] = {A0, A1, A2};
    for (int seg = 0; seg < 3; ++seg) {
        const float* __restrict__ A = Aseg[seg];
        for (int kt = 0; kt < 256; kt += 16) {
            {   // A tile 64x16
                int r = tid >> 2, c0 = (tid & 3) * 4, row = bm + r;
                float4 a = (row < NN) ? *reinterpret_cast<const float4*>(&A[(size_t)row * 256 + kt + c0])
                                      : make_float4(0.f, 0.f, 0.f, 0.f);
                As[c0 + 0][r] = a.x; As[c0 + 1][r] = a.y;
                As[c0 + 2][r] = a.z; As[c0 + 3][r] = a.w;
            }
            {   // B tile 16x64
                int rb = tid >> 4, cb = (tid & 15) * 4;
                float4 b = *reinterpret_cast<const float4*>(
                    &Wcat[(size_t)(seg * 256 + kt + rb) * 1024 + bn + cb]);
                *reinterpret_cast<float4*>(&Bs[rb][cb]) = b;
            }
            __syncthreads();
            #pragma unroll
            for (int k = 0; k < 16; ++k) {
                float4 av = *reinterpret_cast<const float4*>(&As[k][ty * 4]);
                float4 bv = *reinterpret_cast<const float4*>(&Bs[k][tx * 4]);
                const float a4[4] = {av.x, av.y, av.z, av.w};
                const float b4[4] = {bv.x, bv.y, bv.z, bv.w};
                #pragma unroll
                for (int i = 0; i < 4; ++i)
                    #pragma unroll
                    for (int j = 0; j < 4; ++j)
                        acc[i][j] += a4[i] * b4[j];
            }
            __syncthreads();
        }
    }
    #pragma unroll
    for (int i = 0; i < 4; ++i) {
        int row = bm + ty * 4 + i;
        if (row < NN) {
            float4 o = make_float4(acc[i][0], acc[i][1], acc[i][2], acc[i][3]);
            *reinterpret_cast<float4*>(&pre[(size_t)row * 1024 + bn + tx * 4]) = o;
        }
    }
}

// gates + state update
__global__ void gate_kernel(const float* __restrict__ pre, const float* __restrict__ c,
                            const float* __restrict__ bc_i, const float* __restrict__ bc_f,
                            const float* __restrict__ bc_g, const float* __restrict__ bc_o,
                            const float* __restrict__ b_i, const float* __restrict__ b_f,
                            const float* __restrict__ b_g, const float* __restrict__ b_o,
                            const float* __restrict__ w_ci, const float* __restrict__ w_cf,
                            const float* __restrict__ w_co,
                            float* __restrict__ h0p, float* __restrict__ cnp) {
    int idx = blockIdx.x * blockDim.x + threadIdx.x;
    if (idx >= NN * (DH / 4)) return;
    int row = idx >> 6;
    int n4 = (idx & 63) << 2;
    size_t pb = (size_t)row * 1024;
    float4 pi = *reinterpret_cast<const float4*>(&pre[pb + n4]);
    float4 pf = *reinterpret_cast<const float4*>(&pre[pb + 256 + n4]);
    float4 pg = *reinterpret_cast<const float4*>(&pre[pb + 512 + n4]);
    float4 po = *reinterpret_cast<const float4*>(&pre[pb + 768 + n4]);
    float4 cv = *reinterpret_cast<const float4*>(&c[(size_t)row * 256 + n4]);
    float4 vbci = *reinterpret_cast<const float4*>(&bc_i[n4]);
    float4 vbcf = *reinterpret_cast<const float4*>(&bc_f[n4]);
    float4 vbcg = *reinterpret_cast<const float4*>(&bc_g[n4]);
    float4 vbco = *reinterpret_cast<const float4*>(&bc_o[n4]);
    float4 vbi  = *reinterpret_cast<const float4*>(&b_i[n4]);
    float4 vbf  = *reinterpret_cast<const float4*>(&b_f[n4]);
    float4 vbg  = *reinterpret_cast<const float4*>(&b_g[n4]);
    float4 vbo  = *reinterpret_cast<const float4*>(&b_o[n4]);
    float4 vwci = *reinterpret_cast<const float4*>(&w_ci[n4]);
    float4 vwcf = *reinterpret_cast<const float4*>(&w_cf[n4]);
    float4 vwco = *reinterpret_cast<const float4*>(&w_co[n4]);
    float4 cn4, h04;
    const float* PI = (const float*)&pi;  const float* PF = (const float*)&pf;
    const float* PG = (const float*)&pg;  const float* PO = (const float*)&po;
    const float* CV = (const float*)&cv;
    const float* BCI = (const float*)&vbci; const float* BCF = (const float*)&vbcf;
    const float* BCG = (const float*)&vbcg; const float* BCO = (const float*)&vbco;
    const float* BI = (const float*)&vbi;   const float* BF = (const float*)&vbf;
    const float* BG = (const float*)&vbg;   const float* BO = (const float*)&vbo;
    const float* WCI = (const float*)&vwci; const float* WCF = (const float*)&vwcf;
    const float* WCO = (const float*)&vwco;
    float* CN = (float*)&cn4; float* H0 = (float*)&h04;
    #pragma unroll
    for (int j = 0; j < 4; ++j) {
        float iv = sigmoidf_(PI[j] + BCI[j] + BI[j] + WCI[j] * CV[j]);
        float fv = sigmoidf_(PF[j] + BCF[j] + BF[j] + WCF[j] * CV[j]);
        float gv = tanhf(PG[j] + BCG[j] + BG[j]);
        float cn = fv * CV[j] + iv * gv;
        float ov = sigmoidf_(PO[j] + BCO[j] + BO[j] + WCO[j] * cn);
        CN[j] = cn;
        H0[j] = ov * tanhf(cn);
    }
    *reinterpret_cast<float4*>(&cnp[(size_t)row * 256 + n4]) = cn4;
    *reinterpret_cast<float4*>(&h0p[(size_t)row * 256 + n4]) = h04;
}

// out[M x 256] = relu(A) (M x 256) @ B (256 x 256) + bias
__global__ __launch_bounds__(256) void gemm_lin(const float* __restrict__ A,
                                                const float* __restrict__ B,
                                                const float* __restrict__ bias,
                                                float* __restrict__ out) {
    __shared__ float As[16][68];
    __shared__ float Bs[16][68];
    int bm = blockIdx.x * 64;
    int bn = blockIdx.y * 64;
    int tid = threadIdx.x;
    int tx = tid & 15, ty = tid >> 4;
    float acc[4][4] = {};
    for (int kt = 0; kt < 256; kt += 16) {
        {
            int r = tid >> 2, c0 = (tid & 3) * 4, row = bm + r;
            float4 a = (row < NN) ? *reinterpret_cast<const float4*>(&A[(size_t)row * 256 + kt + c0])
                                  : make_float4(0.f, 0.f, 0.f, 0.f);
            As[c0 + 0][r] = fmaxf(a.x, 0.f); As[c0 + 1][r] = fmaxf(a.y, 0.f);
            As[c0 + 2][r] = fmaxf(a.z, 0.f); As[c0 + 3][r] = fmaxf(a.w, 0.f);
        }
        {
            int rb = tid >> 4, cb = (tid & 15) * 4;
            float4 b = *reinterpret_cast<const float4*>(&B[(size_t)(kt + rb) * 256 + bn + cb]);
            *reinterpret_cast<float4*>(&Bs[rb][cb]) = b;
        }
        __syncthreads();
        #pragma unroll
        for (int k = 0; k < 16; ++k) {
            float4 av = *reinterpret_cast<const float4*>(&As[k][ty * 4]);
            float4 bv = *reinterpret_cast<const float4*>(&Bs[k][tx * 4]);
            const float a4[4] = {av.x, av.y, av.z, av.w};
            const float b4[4] = {bv.x, bv.y, bv.z, bv.w};
            #pragma unroll
            for (int i = 0; i < 4; ++i)
                #pragma unroll
                for (int j = 0; j < 4; ++j)
                    acc[i][j] += a4[i] * b4[j];
        }
        __syncthreads();
    }
    float4 bb = *reinterpret_cast<const float4*>(&bias[bn + tx * 4]);
    const float* BB = (const float*)&bb;
    #pragma unroll
    for (int i = 0; i < 4; ++i) {
        int row = bm + ty * 4 + i;
        if (row < NN) {
            float4 o = make_float4(acc[i][0] + BB[0], acc[i][1] + BB[1],
                                   acc[i][2] + BB[2], acc[i][3] + BB[3]);
            *reinterpret_cast<float4*>(&out[(size_t)row * 256 + bn + tx * 4]) = o;
        }
    }
}

extern "C" void kernel_launch(void* const* d_in, const int* in_sizes, int n_in,
                              void* d_out, int out_size, void* d_ws, size_t ws_size,
                              hipStream_t stream) {
    const float* x   = (const float*)d_in[0];
    const int*   ei  = (const int*)d_in[1];
    const float* ew  = (const float*)d_in[2];
    const float* h   = (const float*)d_in[3];
    const float* c   = (const float*)d_in[4];
    const int*   snf = (const int*)d_in[5];
    const int*   dnf = (const int*)d_in[6];
    const float* W_i = (const float*)d_in[7];
    const float* W_f = (const float*)d_in[8];
    const float* W_g = (const float*)d_in[9];
    const float* W_o = (const float*)d_in[10];
    const float* Wc_i = (const float*)d_in[11];
    const float* Wc_f = (const float*)d_in[12];
    const float* Wc_g = (const float*)d_in[13];
    const float* Wc_o = (const float*)d_in[14];
    const float* bc_i = (const float*)d_in[15];
    const float* bc_f = (const float*)d_in[16];
    const float* bc_g = (const float*)d_in[17];
    const float* bc_o = (const float*)d_in[18];
    const float* b_i  = (const float*)d_in[19];
    const float* b_f  = (const float*)d_in[20];
    const float* b_g  = (const float*)d_in[21];
    const float* b_o  = (const float*)d_in[22];
    const float* b_lin = (const float*)d_in[23];
    const float* w_ci = (const float*)d_in[24];
    const float* w_cf = (const float*)d_in[25];
    const float* w_co = (const float*)d_in[26];
    const float* W_lin = (const float*)d_in[27];

    const int* src = ei;        // edge_index[0]
    const int* dst = ei + NE;   // edge_index[1]

    float* out = (float*)d_out;
    float* houtp = out;           // final h_out; temporarily x_new
    float* h0p   = out + NH;      // h0
    float* cnp   = out + 2 * NH;  // final c_new; temporarily t1

    // ---- workspace layout (total = 126,156,800 B, identical footprint to Round 0) ----
    char* ws = (char*)d_ws;
    float* Wcat = (float*)ws;                       // 3,145,728 B
    float* deg  = (float*)(ws + 3145728);           // 131,072 B
    char*  pr   = ws + 3145728 + 131072;
    float* pre  = (float*)pr;                       // 122,880,000 B
    // CSR scratch aliased INSIDE pre region (dead before gemm_pre writes pre):
    int* cnt1 = (int*)pr;                           // 131,072
    int* cnt2 = (int*)(pr + 131072);                // 131,072
    int* row1 = (int*)(pr + 2 * 131072);            // 131,072 (NN+1 used)
    int* row2 = (int*)(pr + 3 * 131072);            // 131,072
    int* cur1 = (int*)(pr + 4 * 131072);            // 131,072
    int* cur2 = (int*)(pr + 5 * 131072);            // 131,072
    int* adj1 = (int*)(pr + 6 * 131072);            // 3,840,000 (2*NE)
    int* adj2 = (int*)(pr + 6 * 131072 + 3840000);  // 1,920,000 (NE)

    float* x_new = houtp;  // alias: dead before gemm_lin writes h_out
    float* t1    = cnp;    // alias: dead before gate_kernel writes c_new

    // 1. zero deg + counters
    hipMemsetAsync(deg, 0, 131072, stream);
    hipMemsetAsync(cnt1, 0, 2 * 131072, stream);  // cnt1 + cnt2 contiguous

    // 2. degree + dinv
    deg_kernel<<<(NE + 255) / 256, 256, 0, stream>>>(src, ew, deg);
    dinv_kernel<<<(NN + 255) / 256, 256, 0, stream>>>(deg);

    // 3. CSR build: count -> scan -> scatter
    count_kernel<<<(NE + 255) / 256, 256, 0, stream>>>(src, dst, cnt1, cnt2);
    scan_kernel<<<1, SCAN_T, 0, stream>>>(cnt1, cnt2, row1, cur1, row2, cur2);
    scatter_kernel<<<(NE + 255) / 256, 256, 0, stream>>>(src, dst, snf, dnf,
                                                         cur1, cur2, adj1, adj2);

    // 4. gathers (atomic-free)
    augment_gather<<<(NN * 64 + 255) / 256, 256, 0, stream>>>(x, row1, adj1, x_new);
    t1_gather<<<(NN * 64 + 255) / 256, 256, 0, stream>>>(h, row2, adj2, src, ew, deg, t1);

    // 5. pack weights, big GEMM (overwrites CSR scratch with pre)
    wcat_kernel<<<(768 * 1024) / 256, 256, 0, stream>>>(W_i, W_f, W_g, W_o,
                                                        Wc_i, Wc_f, Wc_g, Wc_o, Wcat);
    dim3 g1((NN + 63) / 64, 1024 / 64);
    gemm_pre<<<g1, 256, 0, stream>>>(x_new, h, t1, Wcat, pre);

    // 6. gates -> h0, c_new (overwrites t1 region)
    gate_kernel<<<(NN * 64 + 255) / 256, 256, 0, stream>>>(
        pre, c, bc_i, bc_f, bc_g, bc_o, b_i, b_f, b_g, b_o, w_ci, w_cf, w_co, h0p, cnp);

    // 7. h_out = relu(h0) @ W_lin + b_lin (overwrites x_new region)
    dim3 g2((NN + 63) / 64, 256 / 64);
    gemm_lin<<<g2, 256, 0, stream>>>(h0p, W_lin, b_lin, houtp);
}

// Round 4
// 637.337 us; speedup vs baseline: 8.7179x; 1.9407x over previous
//
#include <hip/hip_runtime.h>
#include <math.h>

#define NN 30000
#define NE 480000
#define DH 256
#define NH (NN * DH)
#define MPAD 30080   // 235 * 128

typedef _Float16 f16x4 __attribute__((ext_vector_type(4)));
typedef _Float16 f16x8 __attribute__((ext_vector_type(8)));
typedef float f32x4 __attribute__((ext_vector_type(4)));

static __device__ __forceinline__ float sigmoidf_(float x) {
    return 1.0f / (1.0f + __expf(-x));
}

// async global->LDS, 16B per lane. LDS ptr must be wave-uniform (HW adds lane*16).
static __device__ __forceinline__ void gload16(const _Float16* g, _Float16* l) {
    __builtin_amdgcn_global_load_lds(
        (const __attribute__((address_space(1))) void*)g,
        (__attribute__((address_space(3))) void*)l, 16, 0, 0);
}

// ---------------- graph prep ----------------

__global__ void deg_kernel(const int* __restrict__ src, const float* __restrict__ w,
                           float* __restrict__ deg) {
    int e = blockIdx.x * blockDim.x + threadIdx.x;
    if (e < NE) atomicAdd(&deg[src[e]], w[e]);
}

__global__ void dinv_kernel(float* __restrict__ deg) {
    int v = blockIdx.x * blockDim.x + threadIdx.x;
    if (v < NN) {
        float d = deg[v];
        deg[v] = (d > 0.0f) ? rsqrtf(fmaxf(d, 1e-12f)) : 0.0f;
    }
}

__global__ void count_kernel(const int* __restrict__ src, const int* __restrict__ dst,
                             int* __restrict__ cnt1, int* __restrict__ cnt2) {
    int e = blockIdx.x * blockDim.x + threadIdx.x;
    if (e >= NE) return;
    atomicAdd(&cnt1[src[e]], 1);
    atomicAdd(&cnt1[dst[e]], 1);
    atomicAdd(&cnt2[dst[e]], 1);
}

#define SCAN_T 1024
#define SCAN_CH 30
__global__ __launch_bounds__(SCAN_T) void scan_kernel(const int* __restrict__ cnt1,
                                                      const int* __restrict__ cnt2,
                                                      int* __restrict__ row1, int* __restrict__ cur1,
                                                      int* __restrict__ row2, int* __restrict__ cur2) {
    __shared__ int part[SCAN_T];
    int t = threadIdx.x;
    {
        int base = t * SCAN_CH;
        int vals[SCAN_CH];
        int local = 0;
        #pragma unroll
        for (int i = 0; i < SCAN_CH; ++i) {
            int idx = base + i;
            int v = (idx < NN) ? cnt1[idx] : 0;
            vals[i] = v; local += v;
        }
        part[t] = local;
        __syncthreads();
        for (int off = 1; off < SCAN_T; off <<= 1) {
            int v = part[t];
            int add = (t >= off) ? part[t - off] : 0;
            __syncthreads();
            part[t] = v + add;
            __syncthreads();
        }
        int run = (t == 0) ? 0 : part[t - 1];
        #pragma unroll
        for (int i = 0; i < SCAN_CH; ++i) {
            int idx = base + i;
            if (idx < NN) { row1[idx] = run; cur1[idx] = run; }
            run += vals[i];
        }
        if (t == SCAN_T - 1) row1[NN] = run;
    }
    __syncthreads();
    {
        int base = t * SCAN_CH;
        int vals[SCAN_CH];
        int local = 0;
        #pragma unroll
        for (int i = 0; i < SCAN_CH; ++i) {
            int idx = base + i;
            int v = (idx < NN) ? cnt2[idx] : 0;
            vals[i] = v; local += v;
        }
        part[t] = local;
        __syncthreads();
        for (int off = 1; off < SCAN_T; off <<= 1) {
            int v = part[t];
            int add = (t >= off) ? part[t - off] : 0;
            __syncthreads();
            part[t] = v + add;
            __syncthreads();
        }
        int run = (t == 0) ? 0 : part[t - 1];
        #pragma unroll
        for (int i = 0; i < SCAN_CH; ++i) {
            int idx = base + i;
            if (idx < NN) { row2[idx] = run; cur2[idx] = run; }
            run += vals[i];
        }
        if (t == SCAN_T - 1) row2[NN] = run;
    }
}

__global__ void scatter_kernel(const int* __restrict__ src, const int* __restrict__ dst,
                               const int* __restrict__ snf, const int* __restrict__ dnf,
                               int* __restrict__ cur1, int* __restrict__ cur2,
                               int* __restrict__ adj1, int* __restrict__ adj2) {
    int e = blockIdx.x * blockDim.x + threadIdx.x;
    if (e >= NE) return;
    int s = src[e], d = dst[e];
    int p1 = atomicAdd(&cur1[s], 1); adj1[p1] = snf[e];
    int p2 = atomicAdd(&cur1[d], 1); adj1[p2] = dnf[e];
    int p3 = atomicAdd(&cur2[d], 1); adj2[p3] = e;
}

// ---------------- fp16 conversions ----------------

// out[i] = (f16)in[i], 8 elems/thread, n8 = count/8
__global__ void conv_f16(const float* __restrict__ in, _Float16* __restrict__ out, int n8) {
    int i = blockIdx.x * blockDim.x + threadIdx.x;
    if (i >= n8) return;
    const float4 a = *reinterpret_cast<const float4*>(&in[(size_t)i * 8]);
    const float4 b = *reinterpret_cast<const float4*>(&in[(size_t)i * 8 + 4]);
    f16x8 v;
    v[0] = (_Float16)a.x; v[1] = (_Float16)a.y; v[2] = (_Float16)a.z; v[3] = (_Float16)a.w;
    v[4] = (_Float16)b.x; v[5] = (_Float16)b.y; v[6] = (_Float16)b.z; v[7] = (_Float16)b.w;
    *reinterpret_cast<f16x8*>(&out[(size_t)i * 8]) = v;
}

// A16[row][256+cc*8 ..] = (f16) h[row][cc*8 ..]   (strided dest, row stride 768)
__global__ void conv_hA(const float* __restrict__ h, _Float16* __restrict__ A16) {
    int i = blockIdx.x * blockDim.x + threadIdx.x;
    if (i >= NN * 32) return;
    int row = i >> 5, cc = (i & 31) * 8;
    const float4 a = *reinterpret_cast<const float4*>(&h[(size_t)row * 256 + cc]);
    const float4 b = *reinterpret_cast<const float4*>(&h[(size_t)row * 256 + cc + 4]);
    f16x8 v;
    v[0] = (_Float16)a.x; v[1] = (_Float16)a.y; v[2] = (_Float16)a.z; v[3] = (_Float16)a.w;
    v[4] = (_Float16)b.x; v[5] = (_Float16)b.y; v[6] = (_Float16)b.z; v[7] = (_Float16)b.w;
    *reinterpret_cast<f16x8*>(&A16[(size_t)row * 768 + 256 + cc]) = v;
}

// ---------------- gathers (write fp16 into A16) ----------------

__global__ __launch_bounds__(256) void augment_gather16(const _Float16* __restrict__ x16,
                                                        const int* __restrict__ row1,
                                                        const int* __restrict__ adj1,
                                                        _Float16* __restrict__ A16) {
    int wid = (blockIdx.x * blockDim.x + threadIdx.x) >> 6;
    int l = threadIdx.x & 63;
    if (wid >= NN) return;
    int beg = row1[wid], end = row1[wid + 1];
    f16x4 xv = *reinterpret_cast<const f16x4*>(&x16[(size_t)wid * 256 + l * 4]);
    float a0 = (float)xv[0], a1 = (float)xv[1], a2 = (float)xv[2], a3 = (float)xv[3];
    for (int j = beg; j < end; ++j) {
        int nbr = adj1[j];
        f16x4 v = *reinterpret_cast<const f16x4*>(&x16[(size_t)nbr * 256 + l * 4]);
        a0 += (float)v[0]; a1 += (float)v[1]; a2 += (float)v[2]; a3 += (float)v[3];
    }
    f16x4 o;
    o[0] = (_Float16)a0; o[1] = (_Float16)a1; o[2] = (_Float16)a2; o[3] = (_Float16)a3;
    *reinterpret_cast<f16x4*>(&A16[(size_t)wid * 768 + l * 4]) = o;
}

__global__ __launch_bounds__(256) void t1_gather16(const _Float16* __restrict__ h16,
                                                   const int* __restrict__ row2,
                                                   const int* __restrict__ adj2,
                                                   const int* __restrict__ src,
                                                   const float* __restrict__ w,
                                                   const float* __restrict__ dinv,
                                                   _Float16* __restrict__ A16) {
    int wid = (blockIdx.x * blockDim.x + threadIdx.x) >> 6;
    int l = threadIdx.x & 63;
    if (wid >= NN) return;
    int beg = row2[wid], end = row2[wid + 1];
    float dv = dinv[wid];
    float a0 = 0.f, a1 = 0.f, a2 = 0.f, a3 = 0.f;
    for (int j = beg; j < end; ++j) {
        int e = adj2[j];
        int s = src[e];
        float nrm = -dinv[s] * w[e] * dv;
        f16x4 v = *reinterpret_cast<const f16x4*>(&h16[(size_t)s * 256 + l * 4]);
        a0 += nrm * (float)v[0]; a1 += nrm * (float)v[1];
        a2 += nrm * (float)v[2]; a3 += nrm * (float)v[3];
    }
    f16x4 o;
    o[0] = (_Float16)a0; o[1] = (_Float16)a1; o[2] = (_Float16)a2; o[3] = (_Float16)a3;
    *reinterpret_cast<f16x4*>(&A16[(size_t)wid * 768 + 512 + l * 4]) = o;
}

// ---------------- weight packing (transposed, fp16) ----------------

// WcatT[n][k], n in [0,1024), k in [0,768): rows 0-255 of K = W_*, 256-511 = Wc_*[0],
// 512-767 = Wc_*[1]; n: [0:256)=i, [256:512)=f, [512:768)=g, [768:1024)=o
__global__ void wcatT_kernel(const float* __restrict__ W_i, const float* __restrict__ W_f,
                             const float* __restrict__ W_g, const float* __restrict__ W_o,
                             const float* __restrict__ Wc_i, const float* __restrict__ Wc_f,
                             const float* __restrict__ Wc_g, const float* __restrict__ Wc_o,
                             _Float16* __restrict__ WcatT) {
    int idx = blockIdx.x * blockDim.x + threadIdx.x;
    if (idx >= 768 * 1024) return;
    int k = idx >> 10, n = idx & 1023;   // n fastest -> coalesced reads
    int seg = k >> 8, kk = k & 255, gate = n >> 8, nn = n & 255;
    const float* p;
    if (seg == 0) {
        p = (gate == 0) ? W_i : (gate == 1) ? W_f : (gate == 2) ? W_g : W_o;
    } else {
        const float* base = (gate == 0) ? Wc_i : (gate == 1) ? Wc_f : (gate == 2) ? Wc_g : Wc_o;
        p = base + (seg - 1) * 65536;
    }
    WcatT[(size_t)n * 768 + k] = (_Float16)p[kk * 256 + nn];
}

__global__ void wlinT_kernel(const float* __restrict__ W_lin, _Float16* __restrict__ WlinT) {
    int idx = blockIdx.x * blockDim.x + threadIdx.x;
    if (idx >= 256 * 256) return;
    int k = idx >> 8, n = idx & 255;
    WlinT[(size_t)n * 256 + k] = (_Float16)W_lin[k * 256 + n];
}

// ---------------- fp16 MFMA GEMM ----------------
// C[M x N] = A[M x K] @ B^T[N x K]^T ; 128x128 tile, BK=64, 4 waves (2x2), 16x16x32 f16.
// LDS linear [128][64] f16 per operand; XOR chunk-swizzle (chunk ^= row&7) applied on BOTH
// the global staging source and the ds_read (rule #21) -> 2-way (free) bank conflicts.
template <int K, int N, bool HALF_OUT>
__global__ __launch_bounds__(256) void gemm16(const _Float16* __restrict__ A,
                                              const _Float16* __restrict__ B,
                                              const float* __restrict__ bias,
                                              _Float16* __restrict__ outH,
                                              float* __restrict__ outF) {
    __shared__ _Float16 As[128 * 64];
    __shared__ _Float16 Bs[128 * 64];
    int tid = threadIdx.x;
    int w = tid >> 6, l = tid & 63;
    int wy = w >> 1, wx = w & 1;
    int bm = blockIdx.x * 128, bn = blockIdx.y * 128;

    f32x4 acc[4][4];
    #pragma unroll
    for (int m = 0; m < 4; ++m)
        #pragma unroll
        for (int n = 0; n < 4; ++n)
            acc[m][n] = (f32x4){0.f, 0.f, 0.f, 0.f};

    int rowi = tid >> 3;                      // 0..31
    int g = (tid & 7) ^ (rowi & 7);           // pre-swizzled source chunk
    const _Float16* gA0 = A + (size_t)(bm + rowi) * K + g * 8;
    const _Float16* gB0 = B + (size_t)(bn + rowi) * K + g * 8;

    for (int kt = 0; kt < K; kt += 64) {
        #pragma unroll
        for (int i = 0; i < 4; ++i) {
            gload16(gA0 + kt + (size_t)i * 32 * K, &As[i * 2048 + w * 512]);
            gload16(gB0 + kt + (size_t)i * 32 * K, &Bs[i * 2048 + w * 512]);
        }
        __syncthreads();   // compiler drains vmcnt before barrier

        f16x8 af[4][2], bf[4][2];
        #pragma unroll
        for (int m = 0; m < 4; ++m) {
            int row = wy * 64 + m * 16 + (l & 15);
            #pragma unroll
            for (int ks = 0; ks < 2; ++ks) {
                int ch = (ks * 4 + (l >> 4)) ^ (l & 7);
                af[m][ks] = *reinterpret_cast<const f16x8*>(&As[row * 64 + ch * 8]);
            }
        }
        #pragma unroll
        for (int n = 0; n < 4; ++n) {
            int row = wx * 64 + n * 16 + (l & 15);
            #pragma unroll
            for (int ks = 0; ks < 2; ++ks) {
                int ch = (ks * 4 + (l >> 4)) ^ (l & 7);
                bf[n][ks] = *reinterpret_cast<const f16x8*>(&Bs[row * 64 + ch * 8]);
            }
        }
        #pragma unroll
        for (int ks = 0; ks < 2; ++ks)
            #pragma unroll
            for (int m = 0; m < 4; ++m)
                #pragma unroll
                for (int n = 0; n < 4; ++n)
                    acc[m][n] = __builtin_amdgcn_mfma_f32_16x16x32_f16(
                        af[m][ks], bf[n][ks], acc[m][n], 0, 0, 0);
        __syncthreads();
    }

    // epilogue: C row = (l>>4)*4 + j (within 16), col = l&15  [m89-verified layout]
    #pragma unroll
    for (int m = 0; m < 4; ++m) {
        #pragma unroll
        for (int n = 0; n < 4; ++n) {
            int col = bn + wx * 64 + n * 16 + (l & 15);
            #pragma unroll
            for (int j = 0; j < 4; ++j) {
                int row = bm + wy * 64 + m * 16 + (l >> 4) * 4 + j;
                if (row < NN) {
                    if constexpr (HALF_OUT)
                        outH[(size_t)row * N + col] = (_Float16)acc[m][n][j];
                    else
                        outF[(size_t)row * N + col] = acc[m][n][j] + bias[col];
                }
            }
        }
    }
}

// ---------------- gates ----------------

__global__ void gate_kernel(const _Float16* __restrict__ pre, const float* __restrict__ c,
                            const float* __restrict__ bc_i, const float* __restrict__ bc_f,
                            const float* __restrict__ bc_g, const float* __restrict__ bc_o,
                            const float* __restrict__ b_i, const float* __restrict__ b_f,
                            const float* __restrict__ b_g, const float* __restrict__ b_o,
                            const float* __restrict__ w_ci, const float* __restrict__ w_cf,
                            const float* __restrict__ w_co,
                            float* __restrict__ h0p, float* __restrict__ cnp,
                            _Float16* __restrict__ relu16) {
    int idx = blockIdx.x * blockDim.x + threadIdx.x;
    if (idx >= NN * 64) return;
    int row = idx >> 6;
    int n4 = (idx & 63) << 2;
    size_t pb = (size_t)row * 1024;
    f16x4 pi = *reinterpret_cast<const f16x4*>(&pre[pb + n4]);
    f16x4 pf = *reinterpret_cast<const f16x4*>(&pre[pb + 256 + n4]);
    f16x4 pg = *reinterpret_cast<const f16x4*>(&pre[pb + 512 + n4]);
    f16x4 po = *reinterpret_cast<const f16x4*>(&pre[pb + 768 + n4]);
    float4 cv = *reinterpret_cast<const float4*>(&c[(size_t)row * 256 + n4]);
    float4 vbci = *reinterpret_cast<const float4*>(&bc_i[n4]);
    float4 vbcf = *reinterpret_cast<const float4*>(&bc_f[n4]);
    float4 vbcg = *reinterpret_cast<const float4*>(&bc_g[n4]);
    float4 vbco = *reinterpret_cast<const float4*>(&bc_o[n4]);
    float4 vbi  = *reinterpret_cast<const float4*>(&b_i[n4]);
    float4 vbf  = *reinterpret_cast<const float4*>(&b_f[n4]);
    float4 vbg  = *reinterpret_cast<const float4*>(&b_g[n4]);
    float4 vbo  = *reinterpret_cast<const float4*>(&b_o[n4]);
    float4 vwci = *reinterpret_cast<const float4*>(&w_ci[n4]);
    float4 vwcf = *reinterpret_cast<const float4*>(&w_cf[n4]);
    float4 vwco = *reinterpret_cast<const float4*>(&w_co[n4]);
    const float* CV = (const float*)&cv;
    const float* BCI = (const float*)&vbci; const float* BCF = (const float*)&vbcf;
    const float* BCG = (const float*)&vbcg; const float* BCO = (const float*)&vbco;
    const float* BI = (const float*)&vbi;   const float* BF = (const float*)&vbf;
    const float* BG = (const float*)&vbg;   const float* BO = (const float*)&vbo;
    const float* WCI = (const float*)&vwci; const float* WCF = (const float*)&vwcf;
    const float* WCO = (const float*)&vwco;
    float4 cn4, h04;
    float* CN = (float*)&cn4; float* H0 = (float*)&h04;
    f16x4 rl;
    #pragma unroll
    for (int j = 0; j < 4; ++j) {
        float iv = sigmoidf_((float)pi[j] + BCI[j] + BI[j] + WCI[j] * CV[j]);
        float fv = sigmoidf_((float)pf[j] + BCF[j] + BF[j] + WCF[j] * CV[j]);
        float gv = tanhf((float)pg[j] + BCG[j] + BG[j]);
        float cn = fv * CV[j] + iv * gv;
        float ov = sigmoidf_((float)po[j] + BCO[j] + BO[j] + WCO[j] * cn);
        CN[j] = cn;
        float h0 = ov * tanhf(cn);
        H0[j] = h0;
        rl[j] = (_Float16)fmaxf(h0, 0.f);
    }
    *reinterpret_cast<float4*>(&cnp[(size_t)row * 256 + n4]) = cn4;
    *reinterpret_cast<float4*>(&h0p[(size_t)row * 256 + n4]) = h04;
    *reinterpret_cast<f16x4*>(&relu16[(size_t)row * 256 + n4]) = rl;
}

// ---------------- launch ----------------

extern "C" void kernel_launch(void* const* d_in, const int* in_sizes, int n_in,
                              void* d_out, int out_size, void* d_ws, size_t ws_size,
                              hipStream_t stream) {
    const float* x   = (const float*)d_in[0];
    const int*   ei  = (const int*)d_in[1];
    const float* ew  = (const float*)d_in[2];
    const float* h   = (const float*)d_in[3];
    const float* c   = (const float*)d_in[4];
    const int*   snf = (const int*)d_in[5];
    const int*   dnf = (const int*)d_in[6];
    const float* W_i = (const float*)d_in[7];
    const float* W_f = (const float*)d_in[8];
    const float* W_g = (const float*)d_in[9];
    const float* W_o = (const float*)d_in[10];
    const float* Wc_i = (const float*)d_in[11];
    const float* Wc_f = (const float*)d_in[12];
    const float* Wc_g = (const float*)d_in[13];
    const float* Wc_o = (const float*)d_in[14];
    const float* bc_i = (const float*)d_in[15];
    const float* bc_f = (const float*)d_in[16];
    const float* bc_g = (const float*)d_in[17];
    const float* bc_o = (const float*)d_in[18];
    const float* b_i  = (const float*)d_in[19];
    const float* b_f  = (const float*)d_in[20];
    const float* b_g  = (const float*)d_in[21];
    const float* b_o  = (const float*)d_in[22];
    const float* b_lin = (const float*)d_in[23];
    const float* w_ci = (const float*)d_in[24];
    const float* w_cf = (const float*)d_in[25];
    const float* w_co = (const float*)d_in[26];
    const float* W_lin = (const float*)d_in[27];

    const int* src = ei;
    const int* dst = ei + NE;

    float* out = (float*)d_out;
    float* houtp = out;            // h_out
    float* h0p   = out + NH;       // h0
    float* cnp   = out + 2 * NH;   // c_new

    // ---- workspace layout (124,837,888 B total; ws >= 126,156,800 proven) ----
    char* ws = (char*)d_ws;
    char* pre_base = ws;                                  // pre16: 61,440,000 B
    _Float16* pre16 = (_Float16*)pre_base;
    // aliased inside pre16 (dead before gemm_pre writes):
    int* cnt1 = (int*)pre_base;                           // 131,072
    int* cnt2 = (int*)(pre_base + 131072);
    int* row1 = (int*)(pre_base + 2 * 131072);
    int* row2 = (int*)(pre_base + 3 * 131072);
    int* cur1 = (int*)(pre_base + 4 * 131072);
    int* cur2 = (int*)(pre_base + 5 * 131072);
    int* adj1 = (int*)(pre_base + 6 * 131072);            // 3,840,000
    int* adj2 = (int*)(pre_base + 6 * 131072 + 3840000);  // 1,920,000
    _Float16* h16 = (_Float16*)(pre_base + 6553600);      // 15,360,000 (ends 21.9MB < 61.4MB)

    _Float16* A16 = (_Float16*)(ws + 61440000);           // [30080][768] = 46,202,880 B
    _Float16* A16lin = A16;                               // alias: [30080][256], after gemm_pre
    _Float16* WcatT = (_Float16*)(ws + 107642880);        // 1,572,864 B
    _Float16* WlinT = (_Float16*)(ws + 109215744);        // 131,072 B
    float* deg = (float*)(ws + 109346816);                // 131,072 B
    _Float16* x16 = (_Float16*)(ws + 109477888);          // 15,360,000 B -> 124,837,888

    // 1. init
    hipMemsetAsync(deg, 0, 131072, stream);
    hipMemsetAsync(cnt1, 0, 2 * 131072, stream);

    // 2. degree + dinv
    deg_kernel<<<(NE + 255) / 256, 256, 0, stream>>>(src, ew, deg);
    dinv_kernel<<<(NN + 255) / 256, 256, 0, stream>>>(deg);

    // 3. CSR build
    count_kernel<<<(NE + 255) / 256, 256, 0, stream>>>(src, dst, cnt1, cnt2);
    scan_kernel<<<1, SCAN_T, 0, stream>>>(cnt1, cnt2, row1, cur1, row2, cur2);
    scatter_kernel<<<(NE + 255) / 256, 256, 0, stream>>>(src, dst, snf, dnf,
                                                         cur1, cur2, adj1, adj2);

    // 4. fp16 conversions
    conv_f16<<<3750, 256, 0, stream>>>(x, x16, NN * 32);
    conv_f16<<<3750, 256, 0, stream>>>(h, h16, NN * 32);
    conv_hA<<<3750, 256, 0, stream>>>(h, A16);

    // 5. gathers -> A16 segments
    augment_gather16<<<7500, 256, 0, stream>>>(x16, row1, adj1, A16);
    t1_gather16<<<7500, 256, 0, stream>>>(h16, row2, adj2, src, ew, deg, A16);
    // zero pad rows 30000..30079 (full 768-wide tail is contiguous)
    hipMemsetAsync((char*)A16 + (size_t)NN * 768 * 2, 0, (size_t)(MPAD - NN) * 768 * 2, stream);

    // 6. pack weights
    wcatT_kernel<<<3072, 256, 0, stream>>>(W_i, W_f, W_g, W_o, Wc_i, Wc_f, Wc_g, Wc_o, WcatT);
    wlinT_kernel<<<256, 256, 0, stream>>>(W_lin, WlinT);

    // 7. big GEMM: pre16 = A16 @ WcatT^T
    dim3 g1(MPAD / 128, 1024 / 128);
    gemm16<768, 1024, true><<<g1, 256, 0, stream>>>(A16, WcatT, nullptr, pre16, nullptr);

    // 8. gates (writes h0, c_new outputs + relu(h0) fp16 over A16 base)
    gate_kernel<<<7500, 256, 0, stream>>>(pre16, c, bc_i, bc_f, bc_g, bc_o,
                                          b_i, b_f, b_g, b_o, w_ci, w_cf, w_co,
                                          h0p, cnp, A16lin);
    hipMemsetAsync((char*)A16lin + (size_t)NN * 256 * 2, 0, (size_t)(MPAD - NN) * 256 * 2, stream);

    // 9. h_out = relu(h0) @ W_lin + b_lin
    dim3 g2(MPAD / 128, 256 / 128);
    gemm16<256, 256, false><<<g2, 256, 0, stream>>>(A16lin, WlinT, b_lin, nullptr, houtp);
}

// Round 5
// 381.189 us; speedup vs baseline: 14.5761x; 1.6720x over previous
//
#include <hip/hip_runtime.h>
#include <math.h>

#define NN 30000
#define NE 480000
#define DH 256
#define NH (NN * DH)
#define MPAD 30080   // 235 * 128
#define CAP 64       // slot capacity; deg ~ Poisson(16), P(>63) ~ 1e-55

typedef _Float16 f16x4 __attribute__((ext_vector_type(4)));
typedef _Float16 f16x8 __attribute__((ext_vector_type(8)));
typedef float f32x4 __attribute__((ext_vector_type(4)));

static __device__ __forceinline__ float sigmoidf_(float x) {
    return 1.0f / (1.0f + __expf(-x));
}

// async global->LDS, 16B per lane. LDS ptr must be wave-uniform (HW adds lane*16).
static __device__ __forceinline__ void gload16(const _Float16* g, _Float16* l) {
    __builtin_amdgcn_global_load_lds(
        (const __attribute__((address_space(1))) void*)g,
        (__attribute__((address_space(3))) void*)l, 16, 0, 0);
}

// ---------------- graph prep ----------------

__global__ void deg_kernel(const int* __restrict__ src, const float* __restrict__ w,
                           float* __restrict__ deg) {
    int e = blockIdx.x * blockDim.x + threadIdx.x;
    if (e < NE) atomicAdd(&deg[src[e]], w[e]);
}

__global__ void dinv_kernel(float* __restrict__ deg) {
    int v = blockIdx.x * blockDim.x + threadIdx.x;
    if (v < NN) {
        float d = deg[v];
        deg[v] = (d > 0.0f) ? rsqrtf(fmaxf(d, 1e-12f)) : 0.0f;
    }
}

// One pass: place each edge into the src-keyed out-list (snf) and the dst-keyed
// in-list ({src, dnf, norm}). 2 atomics + 2 scattered writes per edge.
__global__ void scatter2(const int* __restrict__ src, const int* __restrict__ dst,
                         const int* __restrict__ snf, const int* __restrict__ dnf,
                         const float* __restrict__ w, const float* __restrict__ dinv,
                         int* __restrict__ cntS, int* __restrict__ cntD,
                         int* __restrict__ slotS, int4* __restrict__ slotD) {
    int e = blockIdx.x * blockDim.x + threadIdx.x;
    if (e >= NE) return;
    int s = src[e], d = dst[e];
    int pS = atomicAdd(&cntS[s], 1);
    if (pS < CAP) slotS[s * CAP + pS] = snf[e];
    float nrm = -dinv[s] * w[e] * dinv[d];
    int pD = atomicAdd(&cntD[d], 1);
    if (pD < CAP) slotD[d * CAP + pD] = make_int4(s, dnf[e], __float_as_int(nrm), 0);
}

// ---------------- fp16 conversion ----------------

__global__ void conv_f16(const float* __restrict__ in, _Float16* __restrict__ out, int n8) {
    int i = blockIdx.x * blockDim.x + threadIdx.x;
    if (i >= n8) return;
    const float4 a = *reinterpret_cast<const float4*>(&in[(size_t)i * 8]);
    const float4 b = *reinterpret_cast<const float4*>(&in[(size_t)i * 8 + 4]);
    f16x8 v;
    v[0] = (_Float16)a.x; v[1] = (_Float16)a.y; v[2] = (_Float16)a.z; v[3] = (_Float16)a.w;
    v[4] = (_Float16)b.x; v[5] = (_Float16)b.y; v[6] = (_Float16)b.z; v[7] = (_Float16)b.w;
    *reinterpret_cast<f16x8*>(&out[(size_t)i * 8]) = v;
}

// ---------------- fused gather: builds all three A16 segments ----------------
// One wave per node v (64 lanes x 4 features):
//   A16[v][0:256]   = x[v] + sum_out x[snf] + sum_in x[dnf]
//   A16[v][256:512] = h[v]
//   A16[v][512:768] = sum_in norm * h[src]
__global__ __launch_bounds__(256) void fused_gather(const _Float16* __restrict__ x16,
                                                    const _Float16* __restrict__ h16,
                                                    const int* __restrict__ cntS,
                                                    const int* __restrict__ cntD,
                                                    const int* __restrict__ slotS,
                                                    const int4* __restrict__ slotD,
                                                    _Float16* __restrict__ A16) {
    int wid = (blockIdx.x * blockDim.x + threadIdx.x) >> 6;
    int l = threadIdx.x & 63;
    if (wid >= NN) return;
    int nS = min(cntS[wid], CAP);
    int nD = min(cntD[wid], CAP);

    f16x4 xv = *reinterpret_cast<const f16x4*>(&x16[(size_t)wid * 256 + l * 4]);
    float a0 = (float)xv[0], a1 = (float)xv[1], a2 = (float)xv[2], a3 = (float)xv[3];
    float t0 = 0.f, t1 = 0.f, t2 = 0.f, t3 = 0.f;

    const int* pS = &slotS[(size_t)wid * CAP];
    for (int j = 0; j < nS; ++j) {
        int nbr = pS[j];
        f16x4 v = *reinterpret_cast<const f16x4*>(&x16[(size_t)nbr * 256 + l * 4]);
        a0 += (float)v[0]; a1 += (float)v[1]; a2 += (float)v[2]; a3 += (float)v[3];
    }
    const int4* pD = &slotD[(size_t)wid * CAP];
    for (int j = 0; j < nD; ++j) {
        int4 ent = pD[j];
        f16x4 v = *reinterpret_cast<const f16x4*>(&x16[(size_t)ent.y * 256 + l * 4]);
        a0 += (float)v[0]; a1 += (float)v[1]; a2 += (float)v[2]; a3 += (float)v[3];
        float nrm = __int_as_float(ent.z);
        f16x4 hv = *reinterpret_cast<const f16x4*>(&h16[(size_t)ent.x * 256 + l * 4]);
        t0 += nrm * (float)hv[0]; t1 += nrm * (float)hv[1];
        t2 += nrm * (float)hv[2]; t3 += nrm * (float)hv[3];
    }
    f16x4 hrow = *reinterpret_cast<const f16x4*>(&h16[(size_t)wid * 256 + l * 4]);

    f16x4 oX, oT;
    oX[0] = (_Float16)a0; oX[1] = (_Float16)a1; oX[2] = (_Float16)a2; oX[3] = (_Float16)a3;
    oT[0] = (_Float16)t0; oT[1] = (_Float16)t1; oT[2] = (_Float16)t2; oT[3] = (_Float16)t3;
    size_t rb = (size_t)wid * 768;
    *reinterpret_cast<f16x4*>(&A16[rb + l * 4]) = oX;
    *reinterpret_cast<f16x4*>(&A16[rb + 256 + l * 4]) = hrow;
    *reinterpret_cast<f16x4*>(&A16[rb + 512 + l * 4]) = oT;
}

// ---------------- weight packing (transposed, fp16) ----------------

__global__ void wcatT_kernel(const float* __restrict__ W_i, const float* __restrict__ W_f,
                             const float* __restrict__ W_g, const float* __restrict__ W_o,
                             const float* __restrict__ Wc_i, const float* __restrict__ Wc_f,
                             const float* __restrict__ Wc_g, const float* __restrict__ Wc_o,
                             _Float16* __restrict__ WcatT) {
    int idx = blockIdx.x * blockDim.x + threadIdx.x;
    if (idx >= 768 * 1024) return;
    int k = idx >> 10, n = idx & 1023;   // n fastest -> coalesced reads
    int seg = k >> 8, kk = k & 255, gate = n >> 8, nn = n & 255;
    const float* p;
    if (seg == 0) {
        p = (gate == 0) ? W_i : (gate == 1) ? W_f : (gate == 2) ? W_g : W_o;
    } else {
        const float* base = (gate == 0) ? Wc_i : (gate == 1) ? Wc_f : (gate == 2) ? Wc_g : Wc_o;
        p = base + (seg - 1) * 65536;
    }
    WcatT[(size_t)n * 768 + k] = (_Float16)p[kk * 256 + nn];
}

__global__ void wlinT_kernel(const float* __restrict__ W_lin, _Float16* __restrict__ WlinT) {
    int idx = blockIdx.x * blockDim.x + threadIdx.x;
    if (idx >= 256 * 256) return;
    int k = idx >> 8, n = idx & 255;
    WlinT[(size_t)n * 256 + k] = (_Float16)W_lin[k * 256 + n];
}

// ---------------- fp16 MFMA GEMM (128x128 tile, BK=64, both-sides XOR swizzle) ----------------

template <int K, int N, bool HALF_OUT>
__global__ __launch_bounds__(256) void gemm16(const _Float16* __restrict__ A,
                                              const _Float16* __restrict__ B,
                                              const float* __restrict__ bias,
                                              _Float16* __restrict__ outH,
                                              float* __restrict__ outF) {
    __shared__ _Float16 As[128 * 64];
    __shared__ _Float16 Bs[128 * 64];
    int tid = threadIdx.x;
    int w = tid >> 6, l = tid & 63;
    int wy = w >> 1, wx = w & 1;
    int bm = blockIdx.x * 128, bn = blockIdx.y * 128;

    f32x4 acc[4][4];
    #pragma unroll
    for (int m = 0; m < 4; ++m)
        #pragma unroll
        for (int n = 0; n < 4; ++n)
            acc[m][n] = (f32x4){0.f, 0.f, 0.f, 0.f};

    int rowi = tid >> 3;                      // 0..31
    int g = (tid & 7) ^ (rowi & 7);           // pre-swizzled source chunk
    const _Float16* gA0 = A + (size_t)(bm + rowi) * K + g * 8;
    const _Float16* gB0 = B + (size_t)(bn + rowi) * K + g * 8;

    for (int kt = 0; kt < K; kt += 64) {
        #pragma unroll
        for (int i = 0; i < 4; ++i) {
            gload16(gA0 + kt + (size_t)i * 32 * K, &As[i * 2048 + w * 512]);
            gload16(gB0 + kt + (size_t)i * 32 * K, &Bs[i * 2048 + w * 512]);
        }
        __syncthreads();

        f16x8 af[4][2], bf[4][2];
        #pragma unroll
        for (int m = 0; m < 4; ++m) {
            int row = wy * 64 + m * 16 + (l & 15);
            #pragma unroll
            for (int ks = 0; ks < 2; ++ks) {
                int ch = (ks * 4 + (l >> 4)) ^ (l & 7);
                af[m][ks] = *reinterpret_cast<const f16x8*>(&As[row * 64 + ch * 8]);
            }
        }
        #pragma unroll
        for (int n = 0; n < 4; ++n) {
            int row = wx * 64 + n * 16 + (l & 15);
            #pragma unroll
            for (int ks = 0; ks < 2; ++ks) {
                int ch = (ks * 4 + (l >> 4)) ^ (l & 7);
                bf[n][ks] = *reinterpret_cast<const f16x8*>(&Bs[row * 64 + ch * 8]);
            }
        }
        #pragma unroll
        for (int ks = 0; ks < 2; ++ks)
            #pragma unroll
            for (int m = 0; m < 4; ++m)
                #pragma unroll
                for (int n = 0; n < 4; ++n)
                    acc[m][n] = __builtin_amdgcn_mfma_f32_16x16x32_f16(
                        af[m][ks], bf[n][ks], acc[m][n], 0, 0, 0);
        __syncthreads();
    }

    #pragma unroll
    for (int m = 0; m < 4; ++m) {
        #pragma unroll
        for (int n = 0; n < 4; ++n) {
            int col = bn + wx * 64 + n * 16 + (l & 15);
            #pragma unroll
            for (int j = 0; j < 4; ++j) {
                int row = bm + wy * 64 + m * 16 + (l >> 4) * 4 + j;
                if (row < NN) {
                    if constexpr (HALF_OUT)
                        outH[(size_t)row * N + col] = (_Float16)acc[m][n][j];
                    else
                        outF[(size_t)row * N + col] = acc[m][n][j] + bias[col];
                }
            }
        }
    }
}

// ---------------- gates ----------------

__global__ void gate_kernel(const _Float16* __restrict__ pre, const float* __restrict__ c,
                            const float* __restrict__ bc_i, const float* __restrict__ bc_f,
                            const float* __restrict__ bc_g, const float* __restrict__ bc_o,
                            const float* __restrict__ b_i, const float* __restrict__ b_f,
                            const float* __restrict__ b_g, const float* __restrict__ b_o,
                            const float* __restrict__ w_ci, const float* __restrict__ w_cf,
                            const float* __restrict__ w_co,
                            float* __restrict__ h0p, float* __restrict__ cnp,
                            _Float16* __restrict__ relu16) {
    int idx = blockIdx.x * blockDim.x + threadIdx.x;
    if (idx >= NN * 64) return;
    int row = idx >> 6;
    int n4 = (idx & 63) << 2;
    size_t pb = (size_t)row * 1024;
    f16x4 pi = *reinterpret_cast<const f16x4*>(&pre[pb + n4]);
    f16x4 pf = *reinterpret_cast<const f16x4*>(&pre[pb + 256 + n4]);
    f16x4 pg = *reinterpret_cast<const f16x4*>(&pre[pb + 512 + n4]);
    f16x4 po = *reinterpret_cast<const f16x4*>(&pre[pb + 768 + n4]);
    float4 cv = *reinterpret_cast<const float4*>(&c[(size_t)row * 256 + n4]);
    float4 vbci = *reinterpret_cast<const float4*>(&bc_i[n4]);
    float4 vbcf = *reinterpret_cast<const float4*>(&bc_f[n4]);
    float4 vbcg = *reinterpret_cast<const float4*>(&bc_g[n4]);
    float4 vbco = *reinterpret_cast<const float4*>(&bc_o[n4]);
    float4 vbi  = *reinterpret_cast<const float4*>(&b_i[n4]);
    float4 vbf  = *reinterpret_cast<const float4*>(&b_f[n4]);
    float4 vbg  = *reinterpret_cast<const float4*>(&b_g[n4]);
    float4 vbo  = *reinterpret_cast<const float4*>(&b_o[n4]);
    float4 vwci = *reinterpret_cast<const float4*>(&w_ci[n4]);
    float4 vwcf = *reinterpret_cast<const float4*>(&w_cf[n4]);
    float4 vwco = *reinterpret_cast<const float4*>(&w_co[n4]);
    const float* CV = (const float*)&cv;
    const float* BCI = (const float*)&vbci; const float* BCF = (const float*)&vbcf;
    const float* BCG = (const float*)&vbcg; const float* BCO = (const float*)&vbco;
    const float* BI = (const float*)&vbi;   const float* BF = (const float*)&vbf;
    const float* BG = (const float*)&vbg;   const float* BO = (const float*)&vbo;
    const float* WCI = (const float*)&vwci; const float* WCF = (const float*)&vwcf;
    const float* WCO = (const float*)&vwco;
    float4 cn4, h04;
    float* CN = (float*)&cn4; float* H0 = (float*)&h04;
    f16x4 rl;
    #pragma unroll
    for (int j = 0; j < 4; ++j) {
        float iv = sigmoidf_((float)pi[j] + BCI[j] + BI[j] + WCI[j] * CV[j]);
        float fv = sigmoidf_((float)pf[j] + BCF[j] + BF[j] + WCF[j] * CV[j]);
        float gv = tanhf((float)pg[j] + BCG[j] + BG[j]);
        float cn = fv * CV[j] + iv * gv;
        float ov = sigmoidf_((float)po[j] + BCO[j] + BO[j] + WCO[j] * cn);
        CN[j] = cn;
        float h0 = ov * tanhf(cn);
        H0[j] = h0;
        rl[j] = (_Float16)fmaxf(h0, 0.f);
    }
    *reinterpret_cast<float4*>(&cnp[(size_t)row * 256 + n4]) = cn4;
    *reinterpret_cast<float4*>(&h0p[(size_t)row * 256 + n4]) = h04;
    *reinterpret_cast<f16x4*>(&relu16[(size_t)row * 256 + n4]) = rl;
}

// ---------------- launch ----------------

extern "C" void kernel_launch(void* const* d_in, const int* in_sizes, int n_in,
                              void* d_out, int out_size, void* d_ws, size_t ws_size,
                              hipStream_t stream) {
    const float* x   = (const float*)d_in[0];
    const int*   ei  = (const int*)d_in[1];
    const float* ew  = (const float*)d_in[2];
    const float* h   = (const float*)d_in[3];
    const float* c   = (const float*)d_in[4];
    const int*   snf = (const int*)d_in[5];
    const int*   dnf = (const int*)d_in[6];
    const float* W_i = (const float*)d_in[7];
    const float* W_f = (const float*)d_in[8];
    const float* W_g = (const float*)d_in[9];
    const float* W_o = (const float*)d_in[10];
    const float* Wc_i = (const float*)d_in[11];
    const float* Wc_f = (const float*)d_in[12];
    const float* Wc_g = (const float*)d_in[13];
    const float* Wc_o = (const float*)d_in[14];
    const float* bc_i = (const float*)d_in[15];
    const float* bc_f = (const float*)d_in[16];
    const float* bc_g = (const float*)d_in[17];
    const float* bc_o = (const float*)d_in[18];
    const float* b_i  = (const float*)d_in[19];
    const float* b_f  = (const float*)d_in[20];
    const float* b_g  = (const float*)d_in[21];
    const float* b_o  = (const float*)d_in[22];
    const float* b_lin = (const float*)d_in[23];
    const float* w_ci = (const float*)d_in[24];
    const float* w_cf = (const float*)d_in[25];
    const float* w_co = (const float*)d_in[26];
    const float* W_lin = (const float*)d_in[27];

    const int* src = ei;
    const int* dst = ei + NE;

    float* out = (float*)d_out;
    float* houtp = out;            // h_out
    float* h0p   = out + NH;       // h0
    float* cnp   = out + 2 * NH;   // c_new

    // ---- workspace layout (124,837,888 B total; ws >= 126,156,800 proven) ----
    char* ws = (char*)d_ws;
    _Float16* pre16 = (_Float16*)ws;                 // 61,440,000 B
    // aliased inside pre16 (all dead before gemm_pre writes pre16):
    int* cntS = (int*)ws;                            // 131,072
    int* cntD = (int*)(ws + 131072);                 // 131,072
    int* slotS = (int*)(ws + 262144);                // 30000*64*4  = 7,680,000
    int4* slotD = (int4*)(ws + 7942144);             // 30000*64*16 = 30,720,000
    _Float16* h16 = (_Float16*)(ws + 38662144);      // 15,360,000 -> ends 54,022,144

    _Float16* A16 = (_Float16*)(ws + 61440000);      // [30080][768] = 46,202,880 B
    _Float16* A16lin = A16;                          // alias: [30080][256], after gemm_pre
    _Float16* WcatT = (_Float16*)(ws + 107642880);   // 1,572,864 B
    _Float16* WlinT = (_Float16*)(ws + 109215744);   // 131,072 B
    float* deg = (float*)(ws + 109346816);           // 131,072 B
    _Float16* x16 = (_Float16*)(ws + 109477888);     // 15,360,000 B -> 124,837,888

    // 1. init counters
    hipMemsetAsync(deg, 0, 131072, stream);
    hipMemsetAsync(cntS, 0, 262144, stream);   // cntS + cntD contiguous

    // 2. degree + dinv
    deg_kernel<<<(NE + 255) / 256, 256, 0, stream>>>(src, ew, deg);
    dinv_kernel<<<(NN + 255) / 256, 256, 0, stream>>>(deg);

    // 3. fp16 conversions
    conv_f16<<<3750, 256, 0, stream>>>(x, x16, NN * 32);
    conv_f16<<<3750, 256, 0, stream>>>(h, h16, NN * 32);

    // 4. slot-bucket build (one pass, 2 atomics + 2 scattered writes per edge)
    scatter2<<<(NE + 255) / 256, 256, 0, stream>>>(src, dst, snf, dnf, ew, deg,
                                                   cntS, cntD, slotS, slotD);

    // 5. fused gather -> all three A16 segments
    fused_gather<<<7500, 256, 0, stream>>>(x16, h16, cntS, cntD, slotS, slotD, A16);
    hipMemsetAsync((char*)A16 + (size_t)NN * 768 * 2, 0, (size_t)(MPAD - NN) * 768 * 2, stream);

    // 6. pack weights
    wcatT_kernel<<<3072, 256, 0, stream>>>(W_i, W_f, W_g, W_o, Wc_i, Wc_f, Wc_g, Wc_o, WcatT);
    wlinT_kernel<<<256, 256, 0, stream>>>(W_lin, WlinT);

    // 7. big GEMM: pre16 = A16 @ WcatT^T
    dim3 g1(MPAD / 128, 1024 / 128);
    gemm16<768, 1024, true><<<g1, 256, 0, stream>>>(A16, WcatT, nullptr, pre16, nullptr);

    // 8. gates (writes h0, c_new outputs + relu(h0) fp16 over A16 base)
    gate_kernel<<<7500, 256, 0, stream>>>(pre16, c, bc_i, bc_f, bc_g, bc_o,
                                          b_i, b_f, b_g, b_o, w_ci, w_cf, w_co,
                                          h0p, cnp, A16lin);
    hipMemsetAsync((char*)A16lin + (size_t)NN * 256 * 2, 0, (size_t)(MPAD - NN) * 256 * 2, stream);

    // 9. h_out = relu(h0) @ W_lin + b_lin
    dim3 g2(MPAD / 128, 256 / 128);
    gemm16<256, 256, false><<<g2, 256, 0, stream>>>(A16lin, WlinT, b_lin, nullptr, houtp);
}

// Round 6
// 364.257 us; speedup vs baseline: 15.2536x; 1.0465x over previous
//
#include <hip/hip_runtime.h>
#include <math.h>

#define NN 30000
#define NE 480000
#define DH 256
#define NH (NN * DH)
#define MPAD 30080   // 235 * 128
#define CAP 64       // slot capacity; deg ~ Poisson(16), P(>63) ~ 1e-55

typedef _Float16 f16x4 __attribute__((ext_vector_type(4)));
typedef _Float16 f16x8 __attribute__((ext_vector_type(8)));
typedef float f32x4 __attribute__((ext_vector_type(4)));

static __device__ __forceinline__ float sigmoidf_(float x) {
    return 1.0f / (1.0f + __expf(-x));
}

// async global->LDS, 16B per lane. LDS ptr must be wave-uniform (HW adds lane*16).
static __device__ __forceinline__ void gload16(const _Float16* g, _Float16* l) {
    __builtin_amdgcn_global_load_lds(
        (const __attribute__((address_space(1))) void*)g,
        (__attribute__((address_space(3))) void*)l, 16, 0, 0);
}

// ---------------- graph prep ----------------

__global__ void deg_kernel(const int* __restrict__ src, const float* __restrict__ w,
                           float* __restrict__ deg) {
    int e = blockIdx.x * blockDim.x + threadIdx.x;
    if (e < NE) atomicAdd(&deg[src[e]], w[e]);
}

__global__ void dinv_kernel(float* __restrict__ deg) {
    int v = blockIdx.x * blockDim.x + threadIdx.x;
    if (v < NN) {
        float d = deg[v];
        deg[v] = (d > 0.0f) ? rsqrtf(fmaxf(d, 1e-12f)) : 0.0f;
    }
}

// One pass: out-list (snf, 4B) keyed by src; in-list ({src|dnf<<15, norm}, 8B) keyed by dst.
__global__ void scatter2(const int* __restrict__ src, const int* __restrict__ dst,
                         const int* __restrict__ snf, const int* __restrict__ dnf,
                         const float* __restrict__ w, const float* __restrict__ dinv,
                         int* __restrict__ cntS, int* __restrict__ cntD,
                         int* __restrict__ slotS, int2* __restrict__ slotD) {
    int e = blockIdx.x * blockDim.x + threadIdx.x;
    if (e >= NE) return;
    int s = src[e], d = dst[e];
    int pS = atomicAdd(&cntS[s], 1);
    if (pS < CAP) slotS[s * CAP + pS] = snf[e];
    float nrm = -dinv[s] * w[e] * dinv[d];
    int pD = atomicAdd(&cntD[d], 1);
    if (pD < CAP) slotD[d * CAP + pD] = make_int2(s | (dnf[e] << 15), __float_as_int(nrm));
}

// ---------------- fp16 conversion ----------------

__global__ void conv_f16(const float* __restrict__ in, _Float16* __restrict__ out, int n8) {
    int i = blockIdx.x * blockDim.x + threadIdx.x;
    if (i >= n8) return;
    const float4 a = *reinterpret_cast<const float4*>(&in[(size_t)i * 8]);
    const float4 b = *reinterpret_cast<const float4*>(&in[(size_t)i * 8 + 4]);
    f16x8 v;
    v[0] = (_Float16)a.x; v[1] = (_Float16)a.y; v[2] = (_Float16)a.z; v[3] = (_Float16)a.w;
    v[4] = (_Float16)b.x; v[5] = (_Float16)b.y; v[6] = (_Float16)b.z; v[7] = (_Float16)b.w;
    *reinterpret_cast<f16x8*>(&out[(size_t)i * 8]) = v;
}

// ---------------- fused gather, 4-batched for MLP ----------------
// One wave per node v (64 lanes x 4 features):
//   A16[v][0:256]   = x[v] + sum_out x[snf] + sum_in x[dnf]
//   A16[v][256:512] = h[v]
//   A16[v][512:768] = sum_in norm * h[src]
__global__ __launch_bounds__(256) void fused_gather(const _Float16* __restrict__ x16,
                                                    const _Float16* __restrict__ h16,
                                                    const int* __restrict__ cntS,
                                                    const int* __restrict__ cntD,
                                                    const int4* __restrict__ slotS4,
                                                    const int4* __restrict__ slotD4,
                                                    _Float16* __restrict__ A16) {
    int wid = (blockIdx.x * blockDim.x + threadIdx.x) >> 6;
    int l = threadIdx.x & 63;
    if (wid >= NN) return;
    int nS = min(cntS[wid], CAP);
    int nD = min(cntD[wid], CAP);

    f16x4 xv = *reinterpret_cast<const f16x4*>(&x16[(size_t)wid * 256 + l * 4]);
    float a0 = (float)xv[0], a1 = (float)xv[1], a2 = (float)xv[2], a3 = (float)xv[3];
    float t0 = 0.f, t1 = 0.f, t2 = 0.f, t3 = 0.f;

    // ---- out-edges: 4 ids per int4 ----
    const int4* pS = &slotS4[(size_t)wid * (CAP / 4)];
    for (int j = 0; j < nS; j += 4) {
        int4 e = pS[j >> 2];
        f16x4 v0, v1, v2, v3;
        // issue all gathers before accumulating (guards are wave-uniform)
        v0 = *reinterpret_cast<const f16x4*>(&x16[(size_t)e.x * 256 + l * 4]);
        if (j + 1 < nS) v1 = *reinterpret_cast<const f16x4*>(&x16[(size_t)e.y * 256 + l * 4]);
        if (j + 2 < nS) v2 = *reinterpret_cast<const f16x4*>(&x16[(size_t)e.z * 256 + l * 4]);
        if (j + 3 < nS) v3 = *reinterpret_cast<const f16x4*>(&x16[(size_t)e.w * 256 + l * 4]);
        a0 += (float)v0[0]; a1 += (float)v0[1]; a2 += (float)v0[2]; a3 += (float)v0[3];
        if (j + 1 < nS) { a0 += (float)v1[0]; a1 += (float)v1[1]; a2 += (float)v1[2]; a3 += (float)v1[3]; }
        if (j + 2 < nS) { a0 += (float)v2[0]; a1 += (float)v2[1]; a2 += (float)v2[2]; a3 += (float)v2[3]; }
        if (j + 3 < nS) { a0 += (float)v3[0]; a1 += (float)v3[1]; a2 += (float)v3[2]; a3 += (float)v3[3]; }
    }

    // ---- in-edges: 2 packed entries per int4, batch 4 entries (2 x int4) ----
    const int4* pD = &slotD4[(size_t)wid * (CAP / 2)];
    for (int j = 0; j < nD; j += 4) {
        int4 ea = pD[(j >> 2) * 2];
        int4 eb = pD[(j >> 2) * 2 + 1];
        int p0 = ea.x, p1 = ea.z, p2 = eb.x, p3 = eb.z;
        float n0 = __int_as_float(ea.y), n1f = __int_as_float(ea.w);
        float n2f = __int_as_float(eb.y), n3f = __int_as_float(eb.w);
        f16x4 x0, x1, x2, x3, g0, g1, g2, g3;
        x0 = *reinterpret_cast<const f16x4*>(&x16[(size_t)(p0 >> 15) * 256 + l * 4]);
        g0 = *reinterpret_cast<const f16x4*>(&h16[(size_t)(p0 & 0x7fff) * 256 + l * 4]);
        if (j + 1 < nD) {
            x1 = *reinterpret_cast<const f16x4*>(&x16[(size_t)(p1 >> 15) * 256 + l * 4]);
            g1 = *reinterpret_cast<const f16x4*>(&h16[(size_t)(p1 & 0x7fff) * 256 + l * 4]);
        }
        if (j + 2 < nD) {
            x2 = *reinterpret_cast<const f16x4*>(&x16[(size_t)(p2 >> 15) * 256 + l * 4]);
            g2 = *reinterpret_cast<const f16x4*>(&h16[(size_t)(p2 & 0x7fff) * 256 + l * 4]);
        }
        if (j + 3 < nD) {
            x3 = *reinterpret_cast<const f16x4*>(&x16[(size_t)(p3 >> 15) * 256 + l * 4]);
            g3 = *reinterpret_cast<const f16x4*>(&h16[(size_t)(p3 & 0x7fff) * 256 + l * 4]);
        }
        a0 += (float)x0[0]; a1 += (float)x0[1]; a2 += (float)x0[2]; a3 += (float)x0[3];
        t0 += n0 * (float)g0[0]; t1 += n0 * (float)g0[1];
        t2 += n0 * (float)g0[2]; t3 += n0 * (float)g0[3];
        if (j + 1 < nD) {
            a0 += (float)x1[0]; a1 += (float)x1[1]; a2 += (float)x1[2]; a3 += (float)x1[3];
            t0 += n1f * (float)g1[0]; t1 += n1f * (float)g1[1];
            t2 += n1f * (float)g1[2]; t3 += n1f * (float)g1[3];
        }
        if (j + 2 < nD) {
            a0 += (float)x2[0]; a1 += (float)x2[1]; a2 += (float)x2[2]; a3 += (float)x2[3];
            t0 += n2f * (float)g2[0]; t1 += n2f * (float)g2[1];
            t2 += n2f * (float)g2[2]; t3 += n2f * (float)g2[3];
        }
        if (j + 3 < nD) {
            a0 += (float)x3[0]; a1 += (float)x3[1]; a2 += (float)x3[2]; a3 += (float)x3[3];
            t0 += n3f * (float)g3[0]; t1 += n3f * (float)g3[1];
            t2 += n3f * (float)g3[2]; t3 += n3f * (float)g3[3];
        }
    }

    f16x4 hrow = *reinterpret_cast<const f16x4*>(&h16[(size_t)wid * 256 + l * 4]);
    f16x4 oX, oT;
    oX[0] = (_Float16)a0; oX[1] = (_Float16)a1; oX[2] = (_Float16)a2; oX[3] = (_Float16)a3;
    oT[0] = (_Float16)t0; oT[1] = (_Float16)t1; oT[2] = (_Float16)t2; oT[3] = (_Float16)t3;
    size_t rb = (size_t)wid * 768;
    *reinterpret_cast<f16x4*>(&A16[rb + l * 4]) = oX;
    *reinterpret_cast<f16x4*>(&A16[rb + 256 + l * 4]) = hrow;
    *reinterpret_cast<f16x4*>(&A16[rb + 512 + l * 4]) = oT;
}

// ---------------- weight packing (transposed, fp16) ----------------

__global__ void wcatT_kernel(const float* __restrict__ W_i, const float* __restrict__ W_f,
                             const float* __restrict__ W_g, const float* __restrict__ W_o,
                             const float* __restrict__ Wc_i, const float* __restrict__ Wc_f,
                             const float* __restrict__ Wc_g, const float* __restrict__ Wc_o,
                             _Float16* __restrict__ WcatT) {
    int idx = blockIdx.x * blockDim.x + threadIdx.x;
    if (idx >= 768 * 1024) return;
    int k = idx >> 10, n = idx & 1023;   // n fastest -> coalesced reads
    int seg = k >> 8, kk = k & 255, gate = n >> 8, nn = n & 255;
    const float* p;
    if (seg == 0) {
        p = (gate == 0) ? W_i : (gate == 1) ? W_f : (gate == 2) ? W_g : W_o;
    } else {
        const float* base = (gate == 0) ? Wc_i : (gate == 1) ? Wc_f : (gate == 2) ? Wc_g : Wc_o;
        p = base + (seg - 1) * 65536;
    }
    WcatT[(size_t)n * 768 + k] = (_Float16)p[kk * 256 + nn];
}

__global__ void wlinT_kernel(const float* __restrict__ W_lin, _Float16* __restrict__ WlinT) {
    int idx = blockIdx.x * blockDim.x + threadIdx.x;
    if (idx >= 256 * 256) return;
    int k = idx >> 8, n = idx & 255;
    WlinT[(size_t)n * 256 + k] = (_Float16)W_lin[k * 256 + n];
}

// ---------------- fp16 MFMA GEMM (128x128 tile, BK=64, both-sides XOR swizzle) ----------------

template <int K, int N, bool HALF_OUT>
__global__ __launch_bounds__(256) void gemm16(const _Float16* __restrict__ A,
                                              const _Float16* __restrict__ B,
                                              const float* __restrict__ bias,
                                              _Float16* __restrict__ outH,
                                              float* __restrict__ outF) {
    __shared__ _Float16 As[128 * 64];
    __shared__ _Float16 Bs[128 * 64];
    int tid = threadIdx.x;
    int w = tid >> 6, l = tid & 63;
    int wy = w >> 1, wx = w & 1;
    int bm = blockIdx.x * 128, bn = blockIdx.y * 128;

    f32x4 acc[4][4];
    #pragma unroll
    for (int m = 0; m < 4; ++m)
        #pragma unroll
        for (int n = 0; n < 4; ++n)
            acc[m][n] = (f32x4){0.f, 0.f, 0.f, 0.f};

    int rowi = tid >> 3;                      // 0..31
    int g = (tid & 7) ^ (rowi & 7);           // pre-swizzled source chunk
    const _Float16* gA0 = A + (size_t)(bm + rowi) * K + g * 8;
    const _Float16* gB0 = B + (size_t)(bn + rowi) * K + g * 8;

    for (int kt = 0; kt < K; kt += 64) {
        #pragma unroll
        for (int i = 0; i < 4; ++i) {
            gload16(gA0 + kt + (size_t)i * 32 * K, &As[i * 2048 + w * 512]);
            gload16(gB0 + kt + (size_t)i * 32 * K, &Bs[i * 2048 + w * 512]);
        }
        __syncthreads();

        f16x8 af[4][2], bf[4][2];
        #pragma unroll
        for (int m = 0; m < 4; ++m) {
            int row = wy * 64 + m * 16 + (l & 15);
            #pragma unroll
            for (int ks = 0; ks < 2; ++ks) {
                int ch = (ks * 4 + (l >> 4)) ^ (l & 7);
                af[m][ks] = *reinterpret_cast<const f16x8*>(&As[row * 64 + ch * 8]);
            }
        }
        #pragma unroll
        for (int n = 0; n < 4; ++n) {
            int row = wx * 64 + n * 16 + (l & 15);
            #pragma unroll
            for (int ks = 0; ks < 2; ++ks) {
                int ch = (ks * 4 + (l >> 4)) ^ (l & 7);
                bf[n][ks] = *reinterpret_cast<const f16x8*>(&Bs[row * 64 + ch * 8]);
            }
        }
        #pragma unroll
        for (int ks = 0; ks < 2; ++ks)
            #pragma unroll
            for (int m = 0; m < 4; ++m)
                #pragma unroll
                for (int n = 0; n < 4; ++n)
                    acc[m][n] = __builtin_amdgcn_mfma_f32_16x16x32_f16(
                        af[m][ks], bf[n][ks], acc[m][n], 0, 0, 0);
        __syncthreads();
    }

    #pragma unroll
    for (int m = 0; m < 4; ++m) {
        #pragma unroll
        for (int n = 0; n < 4; ++n) {
            int col = bn + wx * 64 + n * 16 + (l & 15);
            #pragma unroll
            for (int j = 0; j < 4; ++j) {
                int row = bm + wy * 64 + m * 16 + (l >> 4) * 4 + j;
                if (row < NN) {
                    if constexpr (HALF_OUT)
                        outH[(size_t)row * N + col] = (_Float16)acc[m][n][j];
                    else
                        outF[(size_t)row * N + col] = acc[m][n][j] + bias[col];
                }
            }
        }
    }
}

// ---------------- gates ----------------

__global__ void gate_kernel(const _Float16* __restrict__ pre, const float* __restrict__ c,
                            const float* __restrict__ bc_i, const float* __restrict__ bc_f,
                            const float* __restrict__ bc_g, const float* __restrict__ bc_o,
                            const float* __restrict__ b_i, const float* __restrict__ b_f,
                            const float* __restrict__ b_g, const float* __restrict__ b_o,
                            const float* __restrict__ w_ci, const float* __restrict__ w_cf,
                            const float* __restrict__ w_co,
                            float* __restrict__ h0p, float* __restrict__ cnp,
                            _Float16* __restrict__ relu16) {
    int idx = blockIdx.x * blockDim.x + threadIdx.x;
    if (idx >= NN * 64) return;
    int row = idx >> 6;
    int n4 = (idx & 63) << 2;
    size_t pb = (size_t)row * 1024;
    f16x4 pi = *reinterpret_cast<const f16x4*>(&pre[pb + n4]);
    f16x4 pf = *reinterpret_cast<const f16x4*>(&pre[pb + 256 + n4]);
    f16x4 pg = *reinterpret_cast<const f16x4*>(&pre[pb + 512 + n4]);
    f16x4 po = *reinterpret_cast<const f16x4*>(&pre[pb + 768 + n4]);
    float4 cv = *reinterpret_cast<const float4*>(&c[(size_t)row * 256 + n4]);
    float4 vbci = *reinterpret_cast<const float4*>(&bc_i[n4]);
    float4 vbcf = *reinterpret_cast<const float4*>(&bc_f[n4]);
    float4 vbcg = *reinterpret_cast<const float4*>(&bc_g[n4]);
    float4 vbco = *reinterpret_cast<const float4*>(&bc_o[n4]);
    float4 vbi  = *reinterpret_cast<const float4*>(&b_i[n4]);
    float4 vbf  = *reinterpret_cast<const float4*>(&b_f[n4]);
    float4 vbg  = *reinterpret_cast<const float4*>(&b_g[n4]);
    float4 vbo  = *reinterpret_cast<const float4*>(&b_o[n4]);
    float4 vwci = *reinterpret_cast<const float4*>(&w_ci[n4]);
    float4 vwcf = *reinterpret_cast<const float4*>(&w_cf[n4]);
    float4 vwco = *reinterpret_cast<const float4*>(&w_co[n4]);
    const float* CV = (const float*)&cv;
    const float* BCI = (const float*)&vbci; const float* BCF = (const float*)&vbcf;
    const float* BCG = (const float*)&vbcg; const float* BCO = (const float*)&vbco;
    const float* BI = (const float*)&vbi;   const float* BF = (const float*)&vbf;
    const float* BG = (const float*)&vbg;   const float* BO = (const float*)&vbo;
    const float* WCI = (const float*)&vwci; const float* WCF = (const float*)&vwcf;
    const float* WCO = (const float*)&vwco;
    float4 cn4, h04;
    float* CN = (float*)&cn4; float* H0 = (float*)&h04;
    f16x4 rl;
    #pragma unroll
    for (int j = 0; j < 4; ++j) {
        float iv = sigmoidf_((float)pi[j] + BCI[j] + BI[j] + WCI[j] * CV[j]);
        float fv = sigmoidf_((float)pf[j] + BCF[j] + BF[j] + WCF[j] * CV[j]);
        float gv = tanhf((float)pg[j] + BCG[j] + BG[j]);
        float cn = fv * CV[j] + iv * gv;
        float ov = sigmoidf_((float)po[j] + BCO[j] + BO[j] + WCO[j] * cn);
        CN[j] = cn;
        float h0 = ov * tanhf(cn);
        H0[j] = h0;
        rl[j] = (_Float16)fmaxf(h0, 0.f);
    }
    *reinterpret_cast<float4*>(&cnp[(size_t)row * 256 + n4]) = cn4;
    *reinterpret_cast<float4*>(&h0p[(size_t)row * 256 + n4]) = h04;
    *reinterpret_cast<f16x4*>(&relu16[(size_t)row * 256 + n4]) = rl;
}

// ---------------- launch ----------------

extern "C" void kernel_launch(void* const* d_in, const int* in_sizes, int n_in,
                              void* d_out, int out_size, void* d_ws, size_t ws_size,
                              hipStream_t stream) {
    const float* x   = (const float*)d_in[0];
    const int*   ei  = (const int*)d_in[1];
    const float* ew  = (const float*)d_in[2];
    const float* h   = (const float*)d_in[3];
    const float* c   = (const float*)d_in[4];
    const int*   snf = (const int*)d_in[5];
    const int*   dnf = (const int*)d_in[6];
    const float* W_i = (const float*)d_in[7];
    const float* W_f = (const float*)d_in[8];
    const float* W_g = (const float*)d_in[9];
    const float* W_o = (const float*)d_in[10];
    const float* Wc_i = (const float*)d_in[11];
    const float* Wc_f = (const float*)d_in[12];
    const float* Wc_g = (const float*)d_in[13];
    const float* Wc_o = (const float*)d_in[14];
    const float* bc_i = (const float*)d_in[15];
    const float* bc_f = (const float*)d_in[16];
    const float* bc_g = (const float*)d_in[17];
    const float* bc_o = (const float*)d_in[18];
    const float* b_i  = (const float*)d_in[19];
    const float* b_f  = (const float*)d_in[20];
    const float* b_g  = (const float*)d_in[21];
    const float* b_o  = (const float*)d_in[22];
    const float* b_lin = (const float*)d_in[23];
    const float* w_ci = (const float*)d_in[24];
    const float* w_cf = (const float*)d_in[25];
    const float* w_co = (const float*)d_in[26];
    const float* W_lin = (const float*)d_in[27];

    const int* src = ei;
    const int* dst = ei + NE;

    float* out = (float*)d_out;
    float* houtp = out;            // h_out
    float* h0p   = out + NH;       // h0
    float* cnp   = out + 2 * NH;   // c_new

    // ---- workspace layout (124,837,888 B total; ws >= 126,156,800 proven) ----
    char* ws = (char*)d_ws;
    _Float16* pre16 = (_Float16*)ws;                 // 61,440,000 B
    // aliased inside pre16 (all dead before gemm_pre writes pre16):
    int* cntS = (int*)ws;                            // 131,072
    int* cntD = (int*)(ws + 131072);                 // 131,072
    int* slotS = (int*)(ws + 262144);                // 30000*64*4 = 7,680,000
    int2* slotD = (int2*)(ws + 7942144);             // 30000*64*8 = 15,360,000
    _Float16* h16 = (_Float16*)(ws + 23302144);      // 15,360,000 -> ends 38,662,144 < 61.44M

    _Float16* A16 = (_Float16*)(ws + 61440000);      // [30080][768] = 46,202,880 B
    _Float16* A16lin = A16;                          // alias: [30080][256], after gemm_pre
    _Float16* WcatT = (_Float16*)(ws + 107642880);   // 1,572,864 B
    _Float16* WlinT = (_Float16*)(ws + 109215744);   // 131,072 B
    float* deg = (float*)(ws + 109346816);           // 131,072 B
    _Float16* x16 = (_Float16*)(ws + 109477888);     // 15,360,000 B -> 124,837,888

    // 1. init counters
    hipMemsetAsync(deg, 0, 131072, stream);
    hipMemsetAsync(cntS, 0, 262144, stream);   // cntS + cntD contiguous

    // 2. degree + dinv
    deg_kernel<<<(NE + 255) / 256, 256, 0, stream>>>(src, ew, deg);
    dinv_kernel<<<(NN + 255) / 256, 256, 0, stream>>>(deg);

    // 3. fp16 conversions
    conv_f16<<<3750, 256, 0, stream>>>(x, x16, NN * 32);
    conv_f16<<<3750, 256, 0, stream>>>(h, h16, NN * 32);

    // 4. slot-bucket build
    scatter2<<<(NE + 255) / 256, 256, 0, stream>>>(src, dst, snf, dnf, ew, deg,
                                                   cntS, cntD, slotS, slotD);

    // 5. fused gather -> all three A16 segments
    fused_gather<<<7500, 256, 0, stream>>>(x16, h16, cntS, cntD,
                                           (const int4*)slotS, (const int4*)slotD, A16);
    hipMemsetAsync((char*)A16 + (size_t)NN * 768 * 2, 0, (size_t)(MPAD - NN) * 768 * 2, stream);

    // 6. pack weights
    wcatT_kernel<<<3072, 256, 0, stream>>>(W_i, W_f, W_g, W_o, Wc_i, Wc_f, Wc_g, Wc_o, WcatT);
    wlinT_kernel<<<256, 256, 0, stream>>>(W_lin, WlinT);

    // 7. big GEMM: pre16 = A16 @ WcatT^T
    dim3 g1(MPAD / 128, 1024 / 128);
    gemm16<768, 1024, true><<<g1, 256, 0, stream>>>(A16, WcatT, nullptr, pre16, nullptr);

    // 8. gates (writes h0, c_new outputs + relu(h0) fp16 over A16 base)
    gate_kernel<<<7500, 256, 0, stream>>>(pre16, c, bc_i, bc_f, bc_g, bc_o,
                                          b_i, b_f, b_g, b_o, w_ci, w_cf, w_co,
                                          h0p, cnp, A16lin);
    hipMemsetAsync((char*)A16lin + (size_t)NN * 256 * 2, 0, (size_t)(MPAD - NN) * 256 * 2, stream);

    // 9. h_out = relu(h0) @ W_lin + b_lin
    dim3 g2(MPAD / 128, 256 / 128);
    gemm16<256, 256, false><<<g2, 256, 0, stream>>>(A16lin, WlinT, b_lin, nullptr, houtp);
}